// Round 18
// baseline (1337.176 us; speedup 1.0000x reference)
//
#include <hip/hip_runtime.h>

#define NPTS    1024
#define DIM     16
#define GRAPHS  64
#define NITERS  20
#define THREADS 1024
#define NWAVES  (THREADS / 64)
#define RT      4        // 16-row tiles per wave (16 waves x 64 rows)
#define NCHUNK  16       // 64 j-tiles, 4 per chunk
#define WINW    80.0f    // prune window, warm two-phase passes
#define WINB    30.0f    // base prune window, fused full passes
#define WREC    55.0f    // mask-record window (prune 30 + stale-drift margin)
#define NWARM   3        // exact two-phase iterations before fused passes
#define MEOCAP  100.0f   // cap on baseline drift-overshoot (exp2 range guard)
#define DRIFTTH 15.0f    // cumulative-drift threshold forcing a mask refresh

typedef __bf16 bf16x8  __attribute__((ext_vector_type(8)));
typedef __bf16 bf16x4v __attribute__((ext_vector_type(4)));
typedef float  f32x4   __attribute__((ext_vector_type(4)));
typedef unsigned long long u64;

#define KLOG 577.07801635558536f      // log2(e)/eps, eps = 0.05^2
#define CLSE 0.0017328679513998633f   // eps*ln2   (KLOG*CLSE == 1)

static __device__ __forceinline__ float fexp2(float x){ return __builtin_amdgcn_exp2f(x); }
static __device__ __forceinline__ float flog2(float x){ return __builtin_amdgcn_logf(x); }

static __device__ __forceinline__ float halfsq16(const float* p)
{
    const float4* v = (const float4*)p;
    float a = 0.0f;
    #pragma unroll
    for (int c = 0; c < 4; ++c) {
        const float4 q = v[c];
        a = fmaf(q.x, q.x, a); a = fmaf(q.y, q.y, a);
        a = fmaf(q.z, q.z, a); a = fmaf(q.w, q.w, a);
    }
    return 0.5f * a;
}

// global f32 cloud -> LDS split-bf16 (hi, lo), optionally pre-scaled
static __device__ __forceinline__ void split_store(
    __bf16* __restrict__ dh, __bf16* __restrict__ dl,
    const float* __restrict__ src, const float scale, const int tid)
{
    const float4* s4 = (const float4*)src;
    #pragma unroll 1
    for (int k = 0; k < (NPTS * DIM / 4) / THREADS; ++k) {
        const int idx = tid + k * THREADS;
        const float4 v = s4[idx];
        const float f0 = v.x * scale, f1 = v.y * scale,
                    f2 = v.z * scale, f3 = v.w * scale;
        bf16x4v h, l;
        h[0] = (__bf16)f0; l[0] = (__bf16)(f0 - (float)h[0]);
        h[1] = (__bf16)f1; l[1] = (__bf16)(f1 - (float)h[1]);
        h[2] = (__bf16)f2; l[2] = (__bf16)(f2 - (float)h[2]);
        h[3] = (__bf16)f3; l[3] = (__bf16)(f3 - (float)h[3]);
        *(bf16x4v*)(dh + idx * 4) = h;
        *(bf16x4v*)(dl + idx * 4) = l;
    }
}

static __device__ __forceinline__ void loadA(
    bf16x8 A[RT], const __bf16* __restrict__ rH, const __bf16* __restrict__ rL,
    const int wbase, const int lane)
{
    const int g = lane >> 4, n = lane & 15, gh = g & 1;
    const __bf16* ap = (g < 2 ? rH : rL) + (wbase + n) * DIM + gh * 8;
    #pragma unroll
    for (int rt = 0; rt < RT; ++rt)
        A[rt] = *(const bf16x8*)(ap + rt * (16 * DIM));
}

// block-uniform magnitude of a published drift (max |max|, |min|)
static __device__ __forceinline__ float dmag(
    const float* __restrict__ dX, const float* __restrict__ dN, const int lane)
{
    float mx = dX[lane], mn = dN[lane];
    #pragma unroll
    for (int d = 1; d < 64; d <<= 1) {
        mx = fmaxf(mx, __shfl_xor(mx, d, 64));
        mn = fminf(mn, __shfl_xor(mn, d, 64));
    }
    return fmaxf(fabsf(mx), fabsf(mn));
}

// Full pruned exp-sum sweep over all 64 j-tiles, 3-deep MFMA rotation.
// Optionally RECORDs the active-tile bitmask (h > -WREC).
template<bool RECORD>
static __device__ __forceinline__ void sweep_sum_full(
    const bf16x8 A[RT], const __bf16* __restrict__ b1p,
    const __bf16* __restrict__ b2p, const float* __restrict__ tp,
    const float me[RT][4], const float win, float s[RT][4],
    u64* __restrict__ rec)
{
    if constexpr (RECORD) {
        #pragma unroll
        for (int r = 0; r < RT; ++r) rec[r] = 0ull;
    }
    #pragma unroll 1
    for (int c = 0; c < NCHUNK; ++c) {
        const int off = c * (4 * 16 * DIM);
        float t[4]; bf16x8 B1[4], B2[4];
        #pragma unroll
        for (int q = 0; q < 4; ++q) {
            t[q]  = tp[c * 64 + q * 16];
            B1[q] = *(const bf16x8*)(b1p + off + q * (16 * DIM));
            B2[q] = *(const bf16x8*)(b2p + off + q * (16 * DIM));
        }
        f32x4 w[3];
        #define ISSUE(kk, slot) do {                                          \
            const int q_ = (kk) >> 2, r_ = (kk) & 3;                          \
            f32x4 a_ = { t[q_] - me[r_][0], t[q_] - me[r_][1],                \
                         t[q_] - me[r_][2], t[q_] - me[r_][3] };              \
            a_ = __builtin_amdgcn_mfma_f32_16x16x32_bf16(A[r_], B2[q_], a_, 0, 0, 0); \
            w[slot] = __builtin_amdgcn_mfma_f32_16x16x32_bf16(A[r_], B1[q_], a_, 0, 0, 0); \
        } while (0)
        ISSUE(0, 0); ISSUE(1, 1);
        #pragma unroll
        for (int k = 0; k < 16; ++k) {
            if (k < 14) ISSUE(k + 2, (k + 2) % 3);
            const f32x4 wc = w[k % 3];
            const int rt = k & 3;
            const float h = fmaxf(fmaxf(wc[0], wc[1]), fmaxf(wc[2], wc[3]));
            if constexpr (RECORD) {
                if (__any(h > -WREC))
                    rec[rt] |= 1ull << (c * 4 + (k >> 2));
            }
            if (__any(h > -win)) {
                s[rt][0] += fexp2(wc[0]);
                s[rt][1] += fexp2(wc[1]);
                s[rt][2] += fexp2(wc[2]);
                s[rt][3] += fexp2(wc[3]);
            }
        }
        #undef ISSUE
    }
}

// Masked sweep: per row-tile (static rt), walk the set bits of its mask in
// pairs with 2-deep MFMA rotation (tile b1's MFMAs hide tile b0's latency).
// No per-tile prune re-check: recorded tiles always exp2 (sub-window terms
// underflow to 0 harmlessly). Mask bits are wave-uniform -> scalar branches.
static __device__ __forceinline__ void sweep_sum_masked(
    const bf16x8 A[RT], const __bf16* __restrict__ b1p,
    const __bf16* __restrict__ b2p, const float* __restrict__ tp,
    const float me[RT][4], float s[RT][4], const u64* __restrict__ msk)
{
    #pragma unroll
    for (int rt = 0; rt < RT; ++rt) {
        const float me0 = me[rt][0], me1 = me[rt][1],
                    me2 = me[rt][2], me3 = me[rt][3];
        float s0 = 0.0f, s1 = 0.0f, s2 = 0.0f, s3 = 0.0f;
        u64 bits = msk[rt];
        #pragma unroll 1
        while (bits) {
            const int b0 = (int)__builtin_ctzll(bits); bits &= bits - 1;
            const float t0 = tp[b0 * 16];
            f32x4 w0 = { t0 - me0, t0 - me1, t0 - me2, t0 - me3 };
            w0 = __builtin_amdgcn_mfma_f32_16x16x32_bf16(
                     A[rt], *(const bf16x8*)(b2p + b0 * 256), w0, 0, 0, 0);
            w0 = __builtin_amdgcn_mfma_f32_16x16x32_bf16(
                     A[rt], *(const bf16x8*)(b1p + b0 * 256), w0, 0, 0, 0);
            const bool has1 = (bits != 0ull);
            f32x4 w1;
            if (has1) {
                const int b1 = (int)__builtin_ctzll(bits); bits &= bits - 1;
                const float t1 = tp[b1 * 16];
                f32x4 a1 = { t1 - me0, t1 - me1, t1 - me2, t1 - me3 };
                a1 = __builtin_amdgcn_mfma_f32_16x16x32_bf16(
                         A[rt], *(const bf16x8*)(b2p + b1 * 256), a1, 0, 0, 0);
                w1 = __builtin_amdgcn_mfma_f32_16x16x32_bf16(
                         A[rt], *(const bf16x8*)(b1p + b1 * 256), a1, 0, 0, 0);
            }
            s0 += fexp2(w0[0]); s1 += fexp2(w0[1]);
            s2 += fexp2(w0[2]); s3 += fexp2(w0[3]);
            if (has1) {
                s0 += fexp2(w1[0]); s1 += fexp2(w1[1]);
                s2 += fexp2(w1[2]); s3 += fexp2(w1[3]);
            }
        }
        s[rt][0] += s0; s[rt][1] += s1; s[rt][2] += s2; s[rt][3] += s3;
    }
}

// Publish epilogue: n==0 lanes write fresh messages (bNew != any buffer read
// this pass) + drift partials vs bOld, then ONE barrier makes all visible.
static __device__ __forceinline__ void publish(
    const float lse[RT][4], const float* __restrict__ bOld,
    float* __restrict__ bNew, float* __restrict__ dOutX,
    float* __restrict__ dOutN, const int wbase, const int lane)
{
    const int g = lane >> 4, n = lane & 15;
    if (n == 0) {
        float dmx = -3.0e38f, dmn = 3.0e38f;
        #pragma unroll
        for (int rt = 0; rt < RT; ++rt) {
            const int row4 = wbase + rt * 16 + g * 4;
            const f32x4 old = *(const f32x4*)(bOld + row4);
            f32x4 mv;
            #pragma unroll
            for (int e = 0; e < 4; ++e) {
                mv[e] = -10.0f - lse[rt][e];
                const float d = mv[e] - old[e];
                dmx = fmaxf(dmx, d); dmn = fminf(dmn, d);
            }
            *(f32x4*)(bNew + row4) = mv;
        }
        dOutX[(wbase >> 4) + g] = dmx;
        dOutN[(wbase >> 4) + g] = dmn;
    }
    __syncthreads();
}

// Warm half-iteration: exact two-phase (max sweep + pruned sum); records mask.
static __device__ __forceinline__ float warm_pass(
    const __bf16* __restrict__ rH, const __bf16* __restrict__ rL,
    const __bf16* __restrict__ cH, const __bf16* __restrict__ cL,
    const float* __restrict__ tOld, const float* __restrict__ bOld,
    float* __restrict__ bNew, float* __restrict__ dOutX,
    float* __restrict__ dOutN, u64* __restrict__ rec,
    const int wbase, const int lane)
{
    const int g = lane >> 4, n = lane & 15, gh = g & 1;
    bf16x8 A[RT];
    loadA(A, rH, rL, wbase, lane);
    const __bf16* b1p = cH + n * DIM + gh * 8;
    const __bf16* b2p = cL + n * DIM + gh * 8;
    const float*  tp  = tOld + n;

    // pass 1: approx row maxima (B = hi only, 2-deep rotation)
    float m[RT][4];
    #pragma unroll
    for (int rt = 0; rt < RT; ++rt)
        #pragma unroll
        for (int e = 0; e < 4; ++e) m[rt][e] = -3.0e38f;

    #pragma unroll 1
    for (int c = 0; c < NCHUNK; ++c) {
        const int off = c * (4 * 16 * DIM);
        float t[4]; bf16x8 B[4];
        #pragma unroll
        for (int q = 0; q < 4; ++q) {
            t[q] = tp[c * 64 + q * 16];
            B[q] = *(const bf16x8*)(b1p + off + q * (16 * DIM));
        }
        f32x4 w[2];
        {
            f32x4 a0 = { t[0], t[0], t[0], t[0] };
            w[0] = __builtin_amdgcn_mfma_f32_16x16x32_bf16(A[0], B[0], a0, 0, 0, 0);
        }
        #pragma unroll
        for (int k = 0; k < 16; ++k) {
            if (k < 15) {
                const int kn = k + 1, qn = kn >> 2, rn = kn & 3;
                f32x4 a = { t[qn], t[qn], t[qn], t[qn] };
                w[kn & 1] = __builtin_amdgcn_mfma_f32_16x16x32_bf16(A[rn], B[qn], a, 0, 0, 0);
            }
            const f32x4 wc = w[k & 1];
            const int rt = k & 3;
            m[rt][0] = fmaxf(m[rt][0], wc[0]);
            m[rt][1] = fmaxf(m[rt][1], wc[1]);
            m[rt][2] = fmaxf(m[rt][2], wc[2]);
            m[rt][3] = fmaxf(m[rt][3], wc[3]);
        }
    }
    #pragma unroll
    for (int rt = 0; rt < RT; ++rt)
        #pragma unroll
        for (int e = 0; e < 4; ++e) {
            float mm = m[rt][e];
            #pragma unroll
            for (int d = 1; d < 16; d <<= 1)
                mm = fmaxf(mm, __shfl_xor(mm, d, 64));
            m[rt][e] = mm;
        }

    // pass 2: pruned exp-sums + mask record
    float s[RT][4];
    #pragma unroll
    for (int rt = 0; rt < RT; ++rt)
        #pragma unroll
        for (int e = 0; e < 4; ++e) s[rt][e] = 0.0f;
    sweep_sum_full<true>(A, b1p, b2p, tp, m, WINW, s, rec);

    float lsum = 0.0f;
    float lse[RT][4];
    #pragma unroll
    for (int rt = 0; rt < RT; ++rt)
        #pragma unroll
        for (int e = 0; e < 4; ++e) {
            float ss = s[rt][e];
            #pragma unroll
            for (int d = 1; d < 16; d <<= 1)
                ss += __shfl_xor(ss, d, 64);
            ss = fmaxf(ss, 1.0e-30f);
            const float l = m[rt][e] + flog2(ss);
            lsum += l;
            lse[rt][e] = l;
        }
    publish(lse, bOld, bNew, dOutX, dOutN, wbase, lane);
    return lsum;
}

// Fused half-iteration: single sweep; me = lse_prev + min(maxDrift, MEOCAP)
// (inductive upper bound on the true row max; cap guards exp2 range —
// active only pre-convergence, which NWARM covers). MASKED walks recorded-
// active tiles only; RECORD refreshes the mask during a full sweep.
template<bool MASKED, bool RECORD>
static __device__ __forceinline__ float fused_pass(
    const __bf16* __restrict__ rH, const __bf16* __restrict__ rL,
    const __bf16* __restrict__ cH, const __bf16* __restrict__ cL,
    const float* __restrict__ tOld, const float* __restrict__ bOld,
    float* __restrict__ bNew,
    const float* __restrict__ dInX, const float* __restrict__ dInN,
    float* __restrict__ dOutX, float* __restrict__ dOutN,
    const u64* __restrict__ msk, u64* __restrict__ rec,
    const int wbase, const int lane)
{
    const int g = lane >> 4, n = lane & 15, gh = g & 1;
    bf16x8 A[RT];
    loadA(A, rH, rL, wbase, lane);

    // drift of the opposite-side messages from the preceding pass
    float dmx = dInX[lane], dmn = dInN[lane];
    #pragma unroll
    for (int d = 1; d < 64; d <<= 1) {
        dmx = fmaxf(dmx, __shfl_xor(dmx, d, 64));
        dmn = fminf(dmn, __shfl_xor(dmn, d, 64));
    }
    const float win  = WINB + fmaxf(0.0f, dmx - dmn);
    const float dmxc = fminf(dmx, MEOCAP);       // exp2-range guard

    float me[RT][4], s[RT][4];
    #pragma unroll
    for (int rt = 0; rt < RT; ++rt) {
        const f32x4 v = *(const f32x4*)(bOld + wbase + rt * 16 + g * 4);
        #pragma unroll
        for (int e = 0; e < 4; ++e) {
            me[rt][e] = (-10.0f - v[e]) + dmxc;  // lse_prev + drift bound
            s[rt][e]  = 0.0f;
        }
    }

    const __bf16* b1p = cH + n * DIM + gh * 8;
    const __bf16* b2p = cL + n * DIM + gh * 8;
    if constexpr (MASKED)
        sweep_sum_masked(A, b1p, b2p, tOld + n, me, s, msk);
    else
        sweep_sum_full<RECORD>(A, b1p, b2p, tOld + n, me, win, s, rec);

    float lsum = 0.0f;
    float lse[RT][4];
    #pragma unroll
    for (int rt = 0; rt < RT; ++rt)
        #pragma unroll
        for (int e = 0; e < 4; ++e) {
            float ss = s[rt][e];
            #pragma unroll
            for (int d = 1; d < 16; d <<= 1)
                ss += __shfl_xor(ss, d, 64);
            ss = fmaxf(ss, 1.0e-30f);
            const float l = me[rt][e] + flog2(ss);
            lsum += l;
            lse[rt][e] = l;
        }
    publish(lse, bOld, bNew, dOutX, dOutN, wbase, lane);
    return lsum;
}

__global__ __launch_bounds__(THREADS)
void sinkhorn_kernel(const float* __restrict__ xg,
                     const float* __restrict__ yg,
                     float* __restrict__ out)
{
    extern __shared__ char ldsraw[];
    __bf16* sxh = (__bf16*)ldsraw;              // [1024][16] hi of K*x
    __bf16* sxl = sxh + NPTS * DIM;
    __bf16* syh = sxl + NPTS * DIM;
    __bf16* syl = syh + NPTS * DIM;
    float*  sF  = (float*)(syl + NPTS * DIM);   // [2][1024] f-messages
    float*  sG  = sF + 2 * NPTS;                // [2][1024] g-messages
    float*  sDfx = sG + 2 * NPTS;               // [2][64] f-drift max
    float*  sDfn = sDfx + 2 * 64;               // [2][64] f-drift min
    float*  sDgx = sDfn + 2 * 64;               // [2][64] g-drift max
    float*  sDgn = sDgx + 2 * 64;               // [2][64] g-drift min

    const int tid   = threadIdx.x;
    const int lane  = tid & 63;
    const int wave  = tid >> 6;
    const int wbase = wave * (RT * 16);

    const int graph = blockIdx.x / 3;
    const int term  = blockIdx.x - graph * 3;   // 0:(x,y) 1:(x,x) 2:(y,y)
    const float* xb = xg + (size_t)graph * (NPTS * DIM);
    const float* yb = yg + (size_t)graph * (NPTS * DIM);
    const float* Xp = (term == 2) ? yb : xb;
    const float* Yp = (term == 1) ? xb : yb;

    split_store(sxh, sxl, Xp, KLOG, tid);       // row side carries 1/eps scale
    split_store(syh, syl, Yp, 1.0f, tid);

    float csum;
    {
        const float hx = halfsq16(Xp + tid * DIM);
        const float hy = halfsq16(Yp + tid * DIM);
        csum = hx + hy;
        sG[NPTS + tid] = fmaf(-KLOG, hy, -10.0f);   // g_{-1} msgs -> gbuf[1]
        sF[NPTS + tid] = 0.0f;                      // finite placeholder
    }
    __syncthreads();

    u64 fmsk[RT], gmsk[RT];                      // wave-uniform tile masks
    float cum = 0.0f;                            // drift since last mask record
    float fsum = 0.0f, gsum = 0.0f;
    #pragma unroll 1
    for (int it = 0; it < NITERS; ++it) {
        const int cur = it & 1, alt = cur ^ 1;
        if (it < NWARM) {
            if (it == NWARM - 1) cum = 0.0f;     // masks recorded this iter
            fsum = warm_pass(sxh, sxl, syh, syl, sG + alt * NPTS,
                             sF + alt * NPTS, sF + cur * NPTS,
                             sDfx + cur * 64, sDfn + cur * 64, fmsk, wbase, lane);
            gsum = warm_pass(syh, syl, sxh, sxl, sF + cur * NPTS,
                             sG + alt * NPTS, sG + cur * NPTS,
                             sDgx + cur * 64, sDgn + cur * 64, gmsk, wbase, lane);
        } else if (cum > DRIFTTH) {              // drift-triggered refresh
            cum = 0.0f;
            fsum = fused_pass<false, true>(sxh, sxl, syh, syl, sG + alt * NPTS,
                              sF + alt * NPTS, sF + cur * NPTS,
                              sDgx + alt * 64, sDgn + alt * 64,
                              sDfx + cur * 64, sDfn + cur * 64,
                              nullptr, fmsk, wbase, lane);
            gsum = fused_pass<false, true>(syh, syl, sxh, sxl, sF + cur * NPTS,
                              sG + alt * NPTS, sG + cur * NPTS,
                              sDfx + cur * 64, sDfn + cur * 64,
                              sDgx + cur * 64, sDgn + cur * 64,
                              nullptr, gmsk, wbase, lane);
        } else {                                  // masked fast passes
            fsum = fused_pass<true, false>(sxh, sxl, syh, syl, sG + alt * NPTS,
                              sF + alt * NPTS, sF + cur * NPTS,
                              sDgx + alt * 64, sDgn + alt * 64,
                              sDfx + cur * 64, sDfn + cur * 64,
                              fmsk, nullptr, wbase, lane);
            gsum = fused_pass<true, false>(syh, syl, sxh, sxl, sF + cur * NPTS,
                              sG + alt * NPTS, sG + cur * NPTS,
                              sDfx + cur * 64, sDfn + cur * 64,
                              sDgx + cur * 64, sDgn + cur * 64,
                              gmsk, nullptr, wbase, lane);
        }
        // accumulate this iteration's published drift (block-uniform)
        if (it >= NWARM - 1)
            cum += dmag(sDfx + cur * 64, sDfn + cur * 64, lane)
                 + dmag(sDgx + cur * 64, sDgn + cur * 64, lane);
    }
    // final f-pass i=20 (cur=0, alt=1), masked (staleness drift-guarded)
    fsum = fused_pass<true, false>(sxh, sxl, syh, syl, sG + 1 * NPTS,
                      sF + 1 * NPTS, sF + 0 * NPTS,
                      sDgx + 1 * 64, sDgn + 1 * 64,
                      sDfx + 0 * 64, sDfn + 0 * 64,
                      fmsk, nullptr, wbase, lane);

    // OT = [csum - CLSE*(sum lse_f + sum lse_g)] / NPTS  (lse sums x16 dup)
    float v = fmaf(-CLSE, (fsum + gsum) * (1.0f / 16.0f), csum);
    #pragma unroll
    for (int off = 32; off; off >>= 1) v += __shfl_down(v, off, 64);
    if (lane == 0) sF[NPTS + wave] = v;          // fbuf[1] is dead
    __syncthreads();
    if (tid == 0) {
        float tot = 0.0f;
        #pragma unroll
        for (int w = 0; w < NWAVES; ++w) tot += sF[NPTS + w];
        const float wgt = ((term == 0) ? 1.0f : -0.5f)
                          / ((float)GRAPHS * (float)NPTS);
        atomicAdd(out, wgt * tot);
    }
}

extern "C" void kernel_launch(void* const* d_in, const int* in_sizes, int n_in,
                              void* d_out, int out_size, void* d_ws, size_t ws_size,
                              hipStream_t stream)
{
    (void)in_sizes; (void)n_in; (void)d_ws; (void)ws_size; (void)out_size;
    const float* x = (const float*)d_in[0];
    const float* y = (const float*)d_in[1];
    float* out = (float*)d_out;

    constexpr size_t LDSB = 4 * NPTS * DIM * sizeof(__bf16)          // 128 KiB
                          + 4 * NPTS * sizeof(float)                 //  16 KiB
                          + 8 * 64 * sizeof(float);                  //   2 KiB
    hipFuncSetAttribute((const void*)sinkhorn_kernel,
                        hipFuncAttributeMaxDynamicSharedMemorySize, (int)LDSB);

    hipMemsetAsync(out, 0, sizeof(float), stream);
    hipLaunchKernelGGL(sinkhorn_kernel, dim3(GRAPHS * 3), dim3(THREADS), LDSB,
                       stream, x, y, out);
}

// Round 19
// 1305.039 us; speedup vs baseline: 1.0246x; 1.0246x over previous
//
#include <hip/hip_runtime.h>

#define NPTS    1024
#define DIM     16
#define GRAPHS  64
#define NITERS  20
#define THREADS 1024
#define NWAVES  (THREADS / 64)
#define RT      4        // 16-row tiles per wave (16 waves x 64 rows)
#define NCHUNK  16       // 64 j-tiles, 4 per chunk
#define WINW    80.0f    // prune window, warm two-phase passes
#define WINB    30.0f    // base prune window, fused full passes
#define WREC    55.0f    // mask-record window (prune 30 + stale-drift margin)
#define NWARM   3        // exact two-phase iterations before fused passes
#define MEOCAP  100.0f   // cap on baseline drift-overshoot (exp2 range guard)
#define DRIFTTH 11.0f    // skip checkpoint refresh when cum drift below this

typedef __bf16 bf16x8  __attribute__((ext_vector_type(8)));
typedef __bf16 bf16x4v __attribute__((ext_vector_type(4)));
typedef float  f32x4   __attribute__((ext_vector_type(4)));
typedef unsigned long long u64;

#define KLOG 577.07801635558536f      // log2(e)/eps, eps = 0.05^2
#define CLSE 0.0017328679513998633f   // eps*ln2   (KLOG*CLSE == 1)

static __device__ __forceinline__ float fexp2(float x){ return __builtin_amdgcn_exp2f(x); }
static __device__ __forceinline__ float flog2(float x){ return __builtin_amdgcn_logf(x); }

static __device__ __forceinline__ float halfsq16(const float* p)
{
    const float4* v = (const float4*)p;
    float a = 0.0f;
    #pragma unroll
    for (int c = 0; c < 4; ++c) {
        const float4 q = v[c];
        a = fmaf(q.x, q.x, a); a = fmaf(q.y, q.y, a);
        a = fmaf(q.z, q.z, a); a = fmaf(q.w, q.w, a);
    }
    return 0.5f * a;
}

// global f32 cloud -> LDS split-bf16 (hi, lo), optionally pre-scaled
static __device__ __forceinline__ void split_store(
    __bf16* __restrict__ dh, __bf16* __restrict__ dl,
    const float* __restrict__ src, const float scale, const int tid)
{
    const float4* s4 = (const float4*)src;
    #pragma unroll 1
    for (int k = 0; k < (NPTS * DIM / 4) / THREADS; ++k) {
        const int idx = tid + k * THREADS;
        const float4 v = s4[idx];
        const float f0 = v.x * scale, f1 = v.y * scale,
                    f2 = v.z * scale, f3 = v.w * scale;
        bf16x4v h, l;
        h[0] = (__bf16)f0; l[0] = (__bf16)(f0 - (float)h[0]);
        h[1] = (__bf16)f1; l[1] = (__bf16)(f1 - (float)h[1]);
        h[2] = (__bf16)f2; l[2] = (__bf16)(f2 - (float)h[2]);
        h[3] = (__bf16)f3; l[3] = (__bf16)(f3 - (float)h[3]);
        *(bf16x4v*)(dh + idx * 4) = h;
        *(bf16x4v*)(dl + idx * 4) = l;
    }
}

static __device__ __forceinline__ void loadA(
    bf16x8 A[RT], const __bf16* __restrict__ rH, const __bf16* __restrict__ rL,
    const int wbase, const int lane)
{
    const int g = lane >> 4, n = lane & 15, gh = g & 1;
    const __bf16* ap = (g < 2 ? rH : rL) + (wbase + n) * DIM + gh * 8;
    #pragma unroll
    for (int rt = 0; rt < RT; ++rt)
        A[rt] = *(const bf16x8*)(ap + rt * (16 * DIM));
}

// block-uniform magnitude of a published drift (max |max|, |min|)
static __device__ __forceinline__ float dmag(
    const float* __restrict__ dX, const float* __restrict__ dN, const int lane)
{
    float mx = dX[lane], mn = dN[lane];
    #pragma unroll
    for (int d = 1; d < 64; d <<= 1) {
        mx = fmaxf(mx, __shfl_xor(mx, d, 64));
        mn = fminf(mn, __shfl_xor(mn, d, 64));
    }
    return fmaxf(fabsf(mx), fabsf(mn));
}

// Full pruned exp-sum sweep over all 64 j-tiles, 3-deep MFMA rotation.
// Optionally RECORDs the active-tile bitmask (h > -WREC).
template<bool RECORD>
static __device__ __forceinline__ void sweep_sum_full(
    const bf16x8 A[RT], const __bf16* __restrict__ b1p,
    const __bf16* __restrict__ b2p, const float* __restrict__ tp,
    const float me[RT][4], const float win, float s[RT][4],
    u64* __restrict__ rec)
{
    if constexpr (RECORD) {
        #pragma unroll
        for (int r = 0; r < RT; ++r) rec[r] = 0ull;
    }
    #pragma unroll 1
    for (int c = 0; c < NCHUNK; ++c) {
        const int off = c * (4 * 16 * DIM);
        float t[4]; bf16x8 B1[4], B2[4];
        #pragma unroll
        for (int q = 0; q < 4; ++q) {
            t[q]  = tp[c * 64 + q * 16];
            B1[q] = *(const bf16x8*)(b1p + off + q * (16 * DIM));
            B2[q] = *(const bf16x8*)(b2p + off + q * (16 * DIM));
        }
        f32x4 w[3];
        #define ISSUE(kk, slot) do {                                          \
            const int q_ = (kk) >> 2, r_ = (kk) & 3;                          \
            f32x4 a_ = { t[q_] - me[r_][0], t[q_] - me[r_][1],                \
                         t[q_] - me[r_][2], t[q_] - me[r_][3] };              \
            a_ = __builtin_amdgcn_mfma_f32_16x16x32_bf16(A[r_], B2[q_], a_, 0, 0, 0); \
            w[slot] = __builtin_amdgcn_mfma_f32_16x16x32_bf16(A[r_], B1[q_], a_, 0, 0, 0); \
        } while (0)
        ISSUE(0, 0); ISSUE(1, 1);
        #pragma unroll
        for (int k = 0; k < 16; ++k) {
            if (k < 14) ISSUE(k + 2, (k + 2) % 3);
            const f32x4 wc = w[k % 3];
            const int rt = k & 3;
            const float h = fmaxf(fmaxf(wc[0], wc[1]), fmaxf(wc[2], wc[3]));
            if constexpr (RECORD) {
                if (__any(h > -WREC))
                    rec[rt] |= 1ull << (c * 4 + (k >> 2));
            }
            if (__any(h > -win)) {
                s[rt][0] += fexp2(wc[0]);
                s[rt][1] += fexp2(wc[1]);
                s[rt][2] += fexp2(wc[2]);
                s[rt][3] += fexp2(wc[3]);
            }
        }
        #undef ISSUE
    }
}

// Masked sweep: per row-tile (static rt), walk the set bits of its mask in
// pairs with 2-deep MFMA rotation (tile b1's MFMAs hide tile b0's latency).
// No per-tile prune re-check: recorded tiles always exp2 (sub-window terms
// underflow to 0 harmlessly). Mask bits are wave-uniform -> scalar branches.
static __device__ __forceinline__ void sweep_sum_masked(
    const bf16x8 A[RT], const __bf16* __restrict__ b1p,
    const __bf16* __restrict__ b2p, const float* __restrict__ tp,
    const float me[RT][4], float s[RT][4], const u64* __restrict__ msk)
{
    #pragma unroll
    for (int rt = 0; rt < RT; ++rt) {
        const float me0 = me[rt][0], me1 = me[rt][1],
                    me2 = me[rt][2], me3 = me[rt][3];
        float s0 = 0.0f, s1 = 0.0f, s2 = 0.0f, s3 = 0.0f;
        u64 bits = msk[rt];
        #pragma unroll 1
        while (bits) {
            const int b0 = (int)__builtin_ctzll(bits); bits &= bits - 1;
            const float t0 = tp[b0 * 16];
            f32x4 w0 = { t0 - me0, t0 - me1, t0 - me2, t0 - me3 };
            w0 = __builtin_amdgcn_mfma_f32_16x16x32_bf16(
                     A[rt], *(const bf16x8*)(b2p + b0 * 256), w0, 0, 0, 0);
            w0 = __builtin_amdgcn_mfma_f32_16x16x32_bf16(
                     A[rt], *(const bf16x8*)(b1p + b0 * 256), w0, 0, 0, 0);
            const bool has1 = (bits != 0ull);
            f32x4 w1;
            if (has1) {
                const int b1 = (int)__builtin_ctzll(bits); bits &= bits - 1;
                const float t1 = tp[b1 * 16];
                f32x4 a1 = { t1 - me0, t1 - me1, t1 - me2, t1 - me3 };
                a1 = __builtin_amdgcn_mfma_f32_16x16x32_bf16(
                         A[rt], *(const bf16x8*)(b2p + b1 * 256), a1, 0, 0, 0);
                w1 = __builtin_amdgcn_mfma_f32_16x16x32_bf16(
                         A[rt], *(const bf16x8*)(b1p + b1 * 256), a1, 0, 0, 0);
            }
            s0 += fexp2(w0[0]); s1 += fexp2(w0[1]);
            s2 += fexp2(w0[2]); s3 += fexp2(w0[3]);
            if (has1) {
                s0 += fexp2(w1[0]); s1 += fexp2(w1[1]);
                s2 += fexp2(w1[2]); s3 += fexp2(w1[3]);
            }
        }
        s[rt][0] += s0; s[rt][1] += s1; s[rt][2] += s2; s[rt][3] += s3;
    }
}

// Publish epilogue: n==0 lanes write fresh messages (bNew != any buffer read
// this pass) + drift partials vs bOld, then ONE barrier makes all visible.
static __device__ __forceinline__ void publish(
    const float lse[RT][4], const float* __restrict__ bOld,
    float* __restrict__ bNew, float* __restrict__ dOutX,
    float* __restrict__ dOutN, const int wbase, const int lane)
{
    const int g = lane >> 4, n = lane & 15;
    if (n == 0) {
        float dmx = -3.0e38f, dmn = 3.0e38f;
        #pragma unroll
        for (int rt = 0; rt < RT; ++rt) {
            const int row4 = wbase + rt * 16 + g * 4;
            const f32x4 old = *(const f32x4*)(bOld + row4);
            f32x4 mv;
            #pragma unroll
            for (int e = 0; e < 4; ++e) {
                mv[e] = -10.0f - lse[rt][e];
                const float d = mv[e] - old[e];
                dmx = fmaxf(dmx, d); dmn = fminf(dmn, d);
            }
            *(f32x4*)(bNew + row4) = mv;
        }
        dOutX[(wbase >> 4) + g] = dmx;
        dOutN[(wbase >> 4) + g] = dmn;
    }
    __syncthreads();
}

// Warm half-iteration: exact two-phase (max sweep + pruned sum); records mask.
static __device__ __forceinline__ float warm_pass(
    const __bf16* __restrict__ rH, const __bf16* __restrict__ rL,
    const __bf16* __restrict__ cH, const __bf16* __restrict__ cL,
    const float* __restrict__ tOld, const float* __restrict__ bOld,
    float* __restrict__ bNew, float* __restrict__ dOutX,
    float* __restrict__ dOutN, u64* __restrict__ rec,
    const int wbase, const int lane)
{
    const int g = lane >> 4, n = lane & 15, gh = g & 1;
    bf16x8 A[RT];
    loadA(A, rH, rL, wbase, lane);
    const __bf16* b1p = cH + n * DIM + gh * 8;
    const __bf16* b2p = cL + n * DIM + gh * 8;
    const float*  tp  = tOld + n;

    // pass 1: approx row maxima (B = hi only, 2-deep rotation)
    float m[RT][4];
    #pragma unroll
    for (int rt = 0; rt < RT; ++rt)
        #pragma unroll
        for (int e = 0; e < 4; ++e) m[rt][e] = -3.0e38f;

    #pragma unroll 1
    for (int c = 0; c < NCHUNK; ++c) {
        const int off = c * (4 * 16 * DIM);
        float t[4]; bf16x8 B[4];
        #pragma unroll
        for (int q = 0; q < 4; ++q) {
            t[q] = tp[c * 64 + q * 16];
            B[q] = *(const bf16x8*)(b1p + off + q * (16 * DIM));
        }
        f32x4 w[2];
        {
            f32x4 a0 = { t[0], t[0], t[0], t[0] };
            w[0] = __builtin_amdgcn_mfma_f32_16x16x32_bf16(A[0], B[0], a0, 0, 0, 0);
        }
        #pragma unroll
        for (int k = 0; k < 16; ++k) {
            if (k < 15) {
                const int kn = k + 1, qn = kn >> 2, rn = kn & 3;
                f32x4 a = { t[qn], t[qn], t[qn], t[qn] };
                w[kn & 1] = __builtin_amdgcn_mfma_f32_16x16x32_bf16(A[rn], B[qn], a, 0, 0, 0);
            }
            const f32x4 wc = w[k & 1];
            const int rt = k & 3;
            m[rt][0] = fmaxf(m[rt][0], wc[0]);
            m[rt][1] = fmaxf(m[rt][1], wc[1]);
            m[rt][2] = fmaxf(m[rt][2], wc[2]);
            m[rt][3] = fmaxf(m[rt][3], wc[3]);
        }
    }
    #pragma unroll
    for (int rt = 0; rt < RT; ++rt)
        #pragma unroll
        for (int e = 0; e < 4; ++e) {
            float mm = m[rt][e];
            #pragma unroll
            for (int d = 1; d < 16; d <<= 1)
                mm = fmaxf(mm, __shfl_xor(mm, d, 64));
            m[rt][e] = mm;
        }

    // pass 2: pruned exp-sums + mask record
    float s[RT][4];
    #pragma unroll
    for (int rt = 0; rt < RT; ++rt)
        #pragma unroll
        for (int e = 0; e < 4; ++e) s[rt][e] = 0.0f;
    sweep_sum_full<true>(A, b1p, b2p, tp, m, WINW, s, rec);

    float lsum = 0.0f;
    float lse[RT][4];
    #pragma unroll
    for (int rt = 0; rt < RT; ++rt)
        #pragma unroll
        for (int e = 0; e < 4; ++e) {
            float ss = s[rt][e];
            #pragma unroll
            for (int d = 1; d < 16; d <<= 1)
                ss += __shfl_xor(ss, d, 64);
            ss = fmaxf(ss, 1.0e-30f);
            const float l = m[rt][e] + flog2(ss);
            lsum += l;
            lse[rt][e] = l;
        }
    publish(lse, bOld, bNew, dOutX, dOutN, wbase, lane);
    return lsum;
}

// Fused half-iteration: single sweep; me = lse_prev + min(maxDrift, MEOCAP)
// (inductive upper bound on the true row max; cap guards exp2 range —
// active only pre-convergence, which NWARM covers). MASKED walks recorded-
// active tiles only; RECORD refreshes the mask during a full sweep.
template<bool MASKED, bool RECORD>
static __device__ __forceinline__ float fused_pass(
    const __bf16* __restrict__ rH, const __bf16* __restrict__ rL,
    const __bf16* __restrict__ cH, const __bf16* __restrict__ cL,
    const float* __restrict__ tOld, const float* __restrict__ bOld,
    float* __restrict__ bNew,
    const float* __restrict__ dInX, const float* __restrict__ dInN,
    float* __restrict__ dOutX, float* __restrict__ dOutN,
    const u64* __restrict__ msk, u64* __restrict__ rec,
    const int wbase, const int lane)
{
    const int g = lane >> 4, n = lane & 15, gh = g & 1;
    bf16x8 A[RT];
    loadA(A, rH, rL, wbase, lane);

    // drift of the opposite-side messages from the preceding pass
    float dmx = dInX[lane], dmn = dInN[lane];
    #pragma unroll
    for (int d = 1; d < 64; d <<= 1) {
        dmx = fmaxf(dmx, __shfl_xor(dmx, d, 64));
        dmn = fminf(dmn, __shfl_xor(dmn, d, 64));
    }
    const float win  = WINB + fmaxf(0.0f, dmx - dmn);
    const float dmxc = fminf(dmx, MEOCAP);       // exp2-range guard

    float me[RT][4], s[RT][4];
    #pragma unroll
    for (int rt = 0; rt < RT; ++rt) {
        const f32x4 v = *(const f32x4*)(bOld + wbase + rt * 16 + g * 4);
        #pragma unroll
        for (int e = 0; e < 4; ++e) {
            me[rt][e] = (-10.0f - v[e]) + dmxc;  // lse_prev + drift bound
            s[rt][e]  = 0.0f;
        }
    }

    const __bf16* b1p = cH + n * DIM + gh * 8;
    const __bf16* b2p = cL + n * DIM + gh * 8;
    if constexpr (MASKED)
        sweep_sum_masked(A, b1p, b2p, tOld + n, me, s, msk);
    else
        sweep_sum_full<RECORD>(A, b1p, b2p, tOld + n, me, win, s, rec);

    float lsum = 0.0f;
    float lse[RT][4];
    #pragma unroll
    for (int rt = 0; rt < RT; ++rt)
        #pragma unroll
        for (int e = 0; e < 4; ++e) {
            float ss = s[rt][e];
            #pragma unroll
            for (int d = 1; d < 16; d <<= 1)
                ss += __shfl_xor(ss, d, 64);
            ss = fmaxf(ss, 1.0e-30f);
            const float l = me[rt][e] + flog2(ss);
            lsum += l;
            lse[rt][e] = l;
        }
    publish(lse, bOld, bNew, dOutX, dOutN, wbase, lane);
    return lsum;
}

__global__ __launch_bounds__(THREADS)
void sinkhorn_kernel(const float* __restrict__ xg,
                     const float* __restrict__ yg,
                     float* __restrict__ out)
{
    extern __shared__ char ldsraw[];
    __bf16* sxh = (__bf16*)ldsraw;              // [1024][16] hi of K*x
    __bf16* sxl = sxh + NPTS * DIM;
    __bf16* syh = sxl + NPTS * DIM;
    __bf16* syl = syh + NPTS * DIM;
    float*  sF  = (float*)(syl + NPTS * DIM);   // [2][1024] f-messages
    float*  sG  = sF + 2 * NPTS;                // [2][1024] g-messages
    float*  sDfx = sG + 2 * NPTS;               // [2][64] f-drift max
    float*  sDfn = sDfx + 2 * 64;               // [2][64] f-drift min
    float*  sDgx = sDfn + 2 * 64;               // [2][64] g-drift max
    float*  sDgn = sDgx + 2 * 64;               // [2][64] g-drift min

    const int tid   = threadIdx.x;
    const int lane  = tid & 63;
    const int wave  = tid >> 6;
    const int wbase = wave * (RT * 16);

    const int graph = blockIdx.x / 3;
    const int term  = blockIdx.x - graph * 3;   // 0:(x,y) 1:(x,x) 2:(y,y)
    const float* xb = xg + (size_t)graph * (NPTS * DIM);
    const float* yb = yg + (size_t)graph * (NPTS * DIM);
    const float* Xp = (term == 2) ? yb : xb;
    const float* Yp = (term == 1) ? xb : yb;

    split_store(sxh, sxl, Xp, KLOG, tid);       // row side carries 1/eps scale
    split_store(syh, syl, Yp, 1.0f, tid);

    float csum;
    {
        const float hx = halfsq16(Xp + tid * DIM);
        const float hy = halfsq16(Yp + tid * DIM);
        csum = hx + hy;
        sG[NPTS + tid] = fmaf(-KLOG, hy, -10.0f);   // g_{-1} msgs -> gbuf[1]
        sF[NPTS + tid] = 0.0f;                      // finite placeholder
    }
    __syncthreads();

    u64 fmsk[RT], gmsk[RT];                      // wave-uniform tile masks
    float cum = 0.0f;                            // drift since last mask record
    float fsum = 0.0f, gsum = 0.0f;
    #pragma unroll 1
    for (int it = 0; it < NITERS; ++it) {
        const int cur = it & 1, alt = cur ^ 1;
        // checkpoint-gated refresh: same checkpoints as the fixed cadence,
        // fires only when accumulated drift threatens the mask budget.
        const bool ckpt = (it >= NWARM) && (((it - NWARM) & 3) == 3);
        if (it < NWARM) {
            if (it == NWARM - 1) cum = 0.0f;     // masks recorded this iter
            fsum = warm_pass(sxh, sxl, syh, syl, sG + alt * NPTS,
                             sF + alt * NPTS, sF + cur * NPTS,
                             sDfx + cur * 64, sDfn + cur * 64, fmsk, wbase, lane);
            gsum = warm_pass(syh, syl, sxh, sxl, sF + cur * NPTS,
                             sG + alt * NPTS, sG + cur * NPTS,
                             sDgx + cur * 64, sDgn + cur * 64, gmsk, wbase, lane);
        } else if (ckpt && cum > DRIFTTH) {      // refresh (straggler path)
            cum = 0.0f;
            fsum = fused_pass<false, true>(sxh, sxl, syh, syl, sG + alt * NPTS,
                              sF + alt * NPTS, sF + cur * NPTS,
                              sDgx + alt * 64, sDgn + alt * 64,
                              sDfx + cur * 64, sDfn + cur * 64,
                              nullptr, fmsk, wbase, lane);
            gsum = fused_pass<false, true>(syh, syl, sxh, sxl, sF + cur * NPTS,
                              sG + alt * NPTS, sG + cur * NPTS,
                              sDfx + cur * 64, sDfn + cur * 64,
                              sDgx + cur * 64, sDgn + cur * 64,
                              nullptr, gmsk, wbase, lane);
        } else {                                  // masked fast passes
            fsum = fused_pass<true, false>(sxh, sxl, syh, syl, sG + alt * NPTS,
                              sF + alt * NPTS, sF + cur * NPTS,
                              sDgx + alt * 64, sDgn + alt * 64,
                              sDfx + cur * 64, sDfn + cur * 64,
                              fmsk, nullptr, wbase, lane);
            gsum = fused_pass<true, false>(syh, syl, sxh, sxl, sF + cur * NPTS,
                              sG + alt * NPTS, sG + cur * NPTS,
                              sDfx + cur * 64, sDfn + cur * 64,
                              sDgx + cur * 64, sDgn + cur * 64,
                              gmsk, nullptr, wbase, lane);
        }
        // accumulate this iteration's published drift (block-uniform)
        if (it >= NWARM - 1)
            cum += dmag(sDfx + cur * 64, sDfn + cur * 64, lane)
                 + dmag(sDgx + cur * 64, sDgn + cur * 64, lane);
    }
    // final f-pass i=20 (cur=0, alt=1), masked (staleness drift-guarded)
    fsum = fused_pass<true, false>(sxh, sxl, syh, syl, sG + 1 * NPTS,
                      sF + 1 * NPTS, sF + 0 * NPTS,
                      sDgx + 1 * 64, sDgn + 1 * 64,
                      sDfx + 0 * 64, sDfn + 0 * 64,
                      fmsk, nullptr, wbase, lane);

    // OT = [csum - CLSE*(sum lse_f + sum lse_g)] / NPTS  (lse sums x16 dup)
    float v = fmaf(-CLSE, (fsum + gsum) * (1.0f / 16.0f), csum);
    #pragma unroll
    for (int off = 32; off; off >>= 1) v += __shfl_down(v, off, 64);
    if (lane == 0) sF[NPTS + wave] = v;          // fbuf[1] is dead
    __syncthreads();
    if (tid == 0) {
        float tot = 0.0f;
        #pragma unroll
        for (int w = 0; w < NWAVES; ++w) tot += sF[NPTS + w];
        const float wgt = ((term == 0) ? 1.0f : -0.5f)
                          / ((float)GRAPHS * (float)NPTS);
        atomicAdd(out, wgt * tot);
    }
}

extern "C" void kernel_launch(void* const* d_in, const int* in_sizes, int n_in,
                              void* d_out, int out_size, void* d_ws, size_t ws_size,
                              hipStream_t stream)
{
    (void)in_sizes; (void)n_in; (void)d_ws; (void)ws_size; (void)out_size;
    const float* x = (const float*)d_in[0];
    const float* y = (const float*)d_in[1];
    float* out = (float*)d_out;

    constexpr size_t LDSB = 4 * NPTS * DIM * sizeof(__bf16)          // 128 KiB
                          + 4 * NPTS * sizeof(float)                 //  16 KiB
                          + 8 * 64 * sizeof(float);                  //   2 KiB
    hipFuncSetAttribute((const void*)sinkhorn_kernel,
                        hipFuncAttributeMaxDynamicSharedMemorySize, (int)LDSB);

    hipMemsetAsync(out, 0, sizeof(float), stream);
    hipLaunchKernelGGL(sinkhorn_kernel, dim3(GRAPHS * 3), dim3(THREADS), LDSB,
                       stream, x, y, out);
}

// Round 20
// 1098.747 us; speedup vs baseline: 1.2170x; 1.1878x over previous
//
#include <hip/hip_runtime.h>

#define NPTS    1024
#define DIM     16
#define GRAPHS  64
#define NITERS  20
#define THREADS 1024
#define NWAVES  (THREADS / 64)
#define RT      4        // 16-row tiles per wave (16 waves x 64 rows)
#define NCHUNK  16       // 64 j-tiles, 4 per chunk
#define WINW    80.0f    // prune window, warm two-phase passes
#define WINB    30.0f    // base prune window, fused full passes
#define WREC    70.0f    // mask-record window (prune 30 + 40 stale-drift budget)
#define NWARM   3        // exact two-phase iterations before fused passes
#define MEOCAP  100.0f   // cap on baseline drift-overshoot (exp2 range guard)

typedef __bf16 bf16x8  __attribute__((ext_vector_type(8)));
typedef __bf16 bf16x4v __attribute__((ext_vector_type(4)));
typedef float  f32x4   __attribute__((ext_vector_type(4)));
typedef unsigned long long u64;

#define KLOG 577.07801635558536f      // log2(e)/eps, eps = 0.05^2
#define CLSE 0.0017328679513998633f   // eps*ln2   (KLOG*CLSE == 1)

static __device__ __forceinline__ float fexp2(float x){ return __builtin_amdgcn_exp2f(x); }
static __device__ __forceinline__ float flog2(float x){ return __builtin_amdgcn_logf(x); }

static __device__ __forceinline__ float halfsq16(const float* p)
{
    const float4* v = (const float4*)p;
    float a = 0.0f;
    #pragma unroll
    for (int c = 0; c < 4; ++c) {
        const float4 q = v[c];
        a = fmaf(q.x, q.x, a); a = fmaf(q.y, q.y, a);
        a = fmaf(q.z, q.z, a); a = fmaf(q.w, q.w, a);
    }
    return 0.5f * a;
}

// global f32 cloud -> LDS split-bf16 (hi, lo), optionally pre-scaled
static __device__ __forceinline__ void split_store(
    __bf16* __restrict__ dh, __bf16* __restrict__ dl,
    const float* __restrict__ src, const float scale, const int tid)
{
    const float4* s4 = (const float4*)src;
    #pragma unroll 1
    for (int k = 0; k < (NPTS * DIM / 4) / THREADS; ++k) {
        const int idx = tid + k * THREADS;
        const float4 v = s4[idx];
        const float f0 = v.x * scale, f1 = v.y * scale,
                    f2 = v.z * scale, f3 = v.w * scale;
        bf16x4v h, l;
        h[0] = (__bf16)f0; l[0] = (__bf16)(f0 - (float)h[0]);
        h[1] = (__bf16)f1; l[1] = (__bf16)(f1 - (float)h[1]);
        h[2] = (__bf16)f2; l[2] = (__bf16)(f2 - (float)h[2]);
        h[3] = (__bf16)f3; l[3] = (__bf16)(f3 - (float)h[3]);
        *(bf16x4v*)(dh + idx * 4) = h;
        *(bf16x4v*)(dl + idx * 4) = l;
    }
}

static __device__ __forceinline__ void loadA(
    bf16x8 A[RT], const __bf16* __restrict__ rH, const __bf16* __restrict__ rL,
    const int wbase, const int lane)
{
    const int g = lane >> 4, n = lane & 15, gh = g & 1;
    const __bf16* ap = (g < 2 ? rH : rL) + (wbase + n) * DIM + gh * 8;
    #pragma unroll
    for (int rt = 0; rt < RT; ++rt)
        A[rt] = *(const bf16x8*)(ap + rt * (16 * DIM));
}

// Full pruned exp-sum sweep over all 64 j-tiles, 3-deep MFMA rotation.
// Optionally RECORDs the active-tile bitmask (h > -WREC).
template<bool RECORD>
static __device__ __forceinline__ void sweep_sum_full(
    const bf16x8 A[RT], const __bf16* __restrict__ b1p,
    const __bf16* __restrict__ b2p, const float* __restrict__ tp,
    const float me[RT][4], const float win, float s[RT][4],
    u64* __restrict__ rec)
{
    if constexpr (RECORD) {
        #pragma unroll
        for (int r = 0; r < RT; ++r) rec[r] = 0ull;
    }
    #pragma unroll 1
    for (int c = 0; c < NCHUNK; ++c) {
        const int off = c * (4 * 16 * DIM);
        float t[4]; bf16x8 B1[4], B2[4];
        #pragma unroll
        for (int q = 0; q < 4; ++q) {
            t[q]  = tp[c * 64 + q * 16];
            B1[q] = *(const bf16x8*)(b1p + off + q * (16 * DIM));
            B2[q] = *(const bf16x8*)(b2p + off + q * (16 * DIM));
        }
        f32x4 w[3];
        #define ISSUE(kk, slot) do {                                          \
            const int q_ = (kk) >> 2, r_ = (kk) & 3;                          \
            f32x4 a_ = { t[q_] - me[r_][0], t[q_] - me[r_][1],                \
                         t[q_] - me[r_][2], t[q_] - me[r_][3] };              \
            a_ = __builtin_amdgcn_mfma_f32_16x16x32_bf16(A[r_], B2[q_], a_, 0, 0, 0); \
            w[slot] = __builtin_amdgcn_mfma_f32_16x16x32_bf16(A[r_], B1[q_], a_, 0, 0, 0); \
        } while (0)
        ISSUE(0, 0); ISSUE(1, 1);
        #pragma unroll
        for (int k = 0; k < 16; ++k) {
            if (k < 14) ISSUE(k + 2, (k + 2) % 3);
            const f32x4 wc = w[k % 3];
            const int rt = k & 3;
            const float h = fmaxf(fmaxf(wc[0], wc[1]), fmaxf(wc[2], wc[3]));
            if constexpr (RECORD) {
                if (__any(h > -WREC))
                    rec[rt] |= 1ull << (c * 4 + (k >> 2));
            }
            if (__any(h > -win)) {
                s[rt][0] += fexp2(wc[0]);
                s[rt][1] += fexp2(wc[1]);
                s[rt][2] += fexp2(wc[2]);
                s[rt][3] += fexp2(wc[3]);
            }
        }
        #undef ISSUE
    }
}

// Masked sweep: per row-tile (static rt), walk the set bits of its mask in
// pairs with 2-deep MFMA rotation (tile b1's MFMAs hide tile b0's latency).
// No per-tile prune re-check: recorded tiles always exp2 (sub-window terms
// underflow to 0 harmlessly). Mask bits are wave-uniform -> scalar branches.
static __device__ __forceinline__ void sweep_sum_masked(
    const bf16x8 A[RT], const __bf16* __restrict__ b1p,
    const __bf16* __restrict__ b2p, const float* __restrict__ tp,
    const float me[RT][4], float s[RT][4], const u64* __restrict__ msk)
{
    #pragma unroll
    for (int rt = 0; rt < RT; ++rt) {
        const float me0 = me[rt][0], me1 = me[rt][1],
                    me2 = me[rt][2], me3 = me[rt][3];
        float s0 = 0.0f, s1 = 0.0f, s2 = 0.0f, s3 = 0.0f;
        u64 bits = msk[rt];
        #pragma unroll 1
        while (bits) {
            const int b0 = (int)__builtin_ctzll(bits); bits &= bits - 1;
            const float t0 = tp[b0 * 16];
            f32x4 w0 = { t0 - me0, t0 - me1, t0 - me2, t0 - me3 };
            w0 = __builtin_amdgcn_mfma_f32_16x16x32_bf16(
                     A[rt], *(const bf16x8*)(b2p + b0 * 256), w0, 0, 0, 0);
            w0 = __builtin_amdgcn_mfma_f32_16x16x32_bf16(
                     A[rt], *(const bf16x8*)(b1p + b0 * 256), w0, 0, 0, 0);
            const bool has1 = (bits != 0ull);
            f32x4 w1;
            if (has1) {
                const int b1 = (int)__builtin_ctzll(bits); bits &= bits - 1;
                const float t1 = tp[b1 * 16];
                f32x4 a1 = { t1 - me0, t1 - me1, t1 - me2, t1 - me3 };
                a1 = __builtin_amdgcn_mfma_f32_16x16x32_bf16(
                         A[rt], *(const bf16x8*)(b2p + b1 * 256), a1, 0, 0, 0);
                w1 = __builtin_amdgcn_mfma_f32_16x16x32_bf16(
                         A[rt], *(const bf16x8*)(b1p + b1 * 256), a1, 0, 0, 0);
            }
            s0 += fexp2(w0[0]); s1 += fexp2(w0[1]);
            s2 += fexp2(w0[2]); s3 += fexp2(w0[3]);
            if (has1) {
                s0 += fexp2(w1[0]); s1 += fexp2(w1[1]);
                s2 += fexp2(w1[2]); s3 += fexp2(w1[3]);
            }
        }
        s[rt][0] += s0; s[rt][1] += s1; s[rt][2] += s2; s[rt][3] += s3;
    }
}

// Publish epilogue: n==0 lanes write fresh messages (bNew != any buffer read
// this pass) + drift partials vs bOld, then ONE barrier makes all visible.
static __device__ __forceinline__ void publish(
    const float lse[RT][4], const float* __restrict__ bOld,
    float* __restrict__ bNew, float* __restrict__ dOutX,
    float* __restrict__ dOutN, const int wbase, const int lane)
{
    const int g = lane >> 4, n = lane & 15;
    if (n == 0) {
        float dmx = -3.0e38f, dmn = 3.0e38f;
        #pragma unroll
        for (int rt = 0; rt < RT; ++rt) {
            const int row4 = wbase + rt * 16 + g * 4;
            const f32x4 old = *(const f32x4*)(bOld + row4);
            f32x4 mv;
            #pragma unroll
            for (int e = 0; e < 4; ++e) {
                mv[e] = -10.0f - lse[rt][e];
                const float d = mv[e] - old[e];
                dmx = fmaxf(dmx, d); dmn = fminf(dmn, d);
            }
            *(f32x4*)(bNew + row4) = mv;
        }
        dOutX[(wbase >> 4) + g] = dmx;
        dOutN[(wbase >> 4) + g] = dmn;
    }
    __syncthreads();
}

// Warm half-iteration: exact two-phase (max sweep + pruned sum); records mask.
static __device__ __forceinline__ float warm_pass(
    const __bf16* __restrict__ rH, const __bf16* __restrict__ rL,
    const __bf16* __restrict__ cH, const __bf16* __restrict__ cL,
    const float* __restrict__ tOld, const float* __restrict__ bOld,
    float* __restrict__ bNew, float* __restrict__ dOutX,
    float* __restrict__ dOutN, u64* __restrict__ rec,
    const int wbase, const int lane)
{
    const int g = lane >> 4, n = lane & 15, gh = g & 1;
    bf16x8 A[RT];
    loadA(A, rH, rL, wbase, lane);
    const __bf16* b1p = cH + n * DIM + gh * 8;
    const __bf16* b2p = cL + n * DIM + gh * 8;
    const float*  tp  = tOld + n;

    // pass 1: approx row maxima (B = hi only, 2-deep rotation)
    float m[RT][4];
    #pragma unroll
    for (int rt = 0; rt < RT; ++rt)
        #pragma unroll
        for (int e = 0; e < 4; ++e) m[rt][e] = -3.0e38f;

    #pragma unroll 1
    for (int c = 0; c < NCHUNK; ++c) {
        const int off = c * (4 * 16 * DIM);
        float t[4]; bf16x8 B[4];
        #pragma unroll
        for (int q = 0; q < 4; ++q) {
            t[q] = tp[c * 64 + q * 16];
            B[q] = *(const bf16x8*)(b1p + off + q * (16 * DIM));
        }
        f32x4 w[2];
        {
            f32x4 a0 = { t[0], t[0], t[0], t[0] };
            w[0] = __builtin_amdgcn_mfma_f32_16x16x32_bf16(A[0], B[0], a0, 0, 0, 0);
        }
        #pragma unroll
        for (int k = 0; k < 16; ++k) {
            if (k < 15) {
                const int kn = k + 1, qn = kn >> 2, rn = kn & 3;
                f32x4 a = { t[qn], t[qn], t[qn], t[qn] };
                w[kn & 1] = __builtin_amdgcn_mfma_f32_16x16x32_bf16(A[rn], B[qn], a, 0, 0, 0);
            }
            const f32x4 wc = w[k & 1];
            const int rt = k & 3;
            m[rt][0] = fmaxf(m[rt][0], wc[0]);
            m[rt][1] = fmaxf(m[rt][1], wc[1]);
            m[rt][2] = fmaxf(m[rt][2], wc[2]);
            m[rt][3] = fmaxf(m[rt][3], wc[3]);
        }
    }
    #pragma unroll
    for (int rt = 0; rt < RT; ++rt)
        #pragma unroll
        for (int e = 0; e < 4; ++e) {
            float mm = m[rt][e];
            #pragma unroll
            for (int d = 1; d < 16; d <<= 1)
                mm = fmaxf(mm, __shfl_xor(mm, d, 64));
            m[rt][e] = mm;
        }

    // pass 2: pruned exp-sums + mask record
    float s[RT][4];
    #pragma unroll
    for (int rt = 0; rt < RT; ++rt)
        #pragma unroll
        for (int e = 0; e < 4; ++e) s[rt][e] = 0.0f;
    sweep_sum_full<true>(A, b1p, b2p, tp, m, WINW, s, rec);

    float lsum = 0.0f;
    float lse[RT][4];
    #pragma unroll
    for (int rt = 0; rt < RT; ++rt)
        #pragma unroll
        for (int e = 0; e < 4; ++e) {
            float ss = s[rt][e];
            #pragma unroll
            for (int d = 1; d < 16; d <<= 1)
                ss += __shfl_xor(ss, d, 64);
            ss = fmaxf(ss, 1.0e-30f);
            const float l = m[rt][e] + flog2(ss);
            lsum += l;
            lse[rt][e] = l;
        }
    publish(lse, bOld, bNew, dOutX, dOutN, wbase, lane);
    return lsum;
}

// Fused half-iteration: single sweep; me = lse_prev + min(maxDrift, MEOCAP)
// (inductive upper bound on the true row max; cap guards exp2 range —
// active only pre-convergence, which NWARM covers). MASKED walks recorded-
// active tiles only; RECORD refreshes the mask during a full sweep.
template<bool MASKED, bool RECORD>
static __device__ __forceinline__ float fused_pass(
    const __bf16* __restrict__ rH, const __bf16* __restrict__ rL,
    const __bf16* __restrict__ cH, const __bf16* __restrict__ cL,
    const float* __restrict__ tOld, const float* __restrict__ bOld,
    float* __restrict__ bNew,
    const float* __restrict__ dInX, const float* __restrict__ dInN,
    float* __restrict__ dOutX, float* __restrict__ dOutN,
    const u64* __restrict__ msk, u64* __restrict__ rec,
    const int wbase, const int lane)
{
    const int g = lane >> 4, n = lane & 15, gh = g & 1;
    bf16x8 A[RT];
    loadA(A, rH, rL, wbase, lane);

    // drift of the opposite-side messages from the preceding pass
    float dmx = dInX[lane], dmn = dInN[lane];
    #pragma unroll
    for (int d = 1; d < 64; d <<= 1) {
        dmx = fmaxf(dmx, __shfl_xor(dmx, d, 64));
        dmn = fminf(dmn, __shfl_xor(dmn, d, 64));
    }
    const float win  = WINB + fmaxf(0.0f, dmx - dmn);
    const float dmxc = fminf(dmx, MEOCAP);       // exp2-range guard

    float me[RT][4], s[RT][4];
    #pragma unroll
    for (int rt = 0; rt < RT; ++rt) {
        const f32x4 v = *(const f32x4*)(bOld + wbase + rt * 16 + g * 4);
        #pragma unroll
        for (int e = 0; e < 4; ++e) {
            me[rt][e] = (-10.0f - v[e]) + dmxc;  // lse_prev + drift bound
            s[rt][e]  = 0.0f;
        }
    }

    const __bf16* b1p = cH + n * DIM + gh * 8;
    const __bf16* b2p = cL + n * DIM + gh * 8;
    if constexpr (MASKED)
        sweep_sum_masked(A, b1p, b2p, tOld + n, me, s, msk);
    else
        sweep_sum_full<RECORD>(A, b1p, b2p, tOld + n, me, win, s, rec);

    float lsum = 0.0f;
    float lse[RT][4];
    #pragma unroll
    for (int rt = 0; rt < RT; ++rt)
        #pragma unroll
        for (int e = 0; e < 4; ++e) {
            float ss = s[rt][e];
            #pragma unroll
            for (int d = 1; d < 16; d <<= 1)
                ss += __shfl_xor(ss, d, 64);
            ss = fmaxf(ss, 1.0e-30f);
            const float l = me[rt][e] + flog2(ss);
            lsum += l;
            lse[rt][e] = l;
        }
    publish(lse, bOld, bNew, dOutX, dOutN, wbase, lane);
    return lsum;
}

__global__ __launch_bounds__(THREADS)
void sinkhorn_kernel(const float* __restrict__ xg,
                     const float* __restrict__ yg,
                     float* __restrict__ out)
{
    extern __shared__ char ldsraw[];
    __bf16* sxh = (__bf16*)ldsraw;              // [1024][16] hi of K*x
    __bf16* sxl = sxh + NPTS * DIM;
    __bf16* syh = sxl + NPTS * DIM;
    __bf16* syl = syh + NPTS * DIM;
    float*  sF  = (float*)(syl + NPTS * DIM);   // [2][1024] f-messages
    float*  sG  = sF + 2 * NPTS;                // [2][1024] g-messages
    float*  sDfx = sG + 2 * NPTS;               // [2][64] f-drift max
    float*  sDfn = sDfx + 2 * 64;               // [2][64] f-drift min
    float*  sDgx = sDfn + 2 * 64;               // [2][64] g-drift max
    float*  sDgn = sDgx + 2 * 64;               // [2][64] g-drift min

    const int tid   = threadIdx.x;
    const int lane  = tid & 63;
    const int wave  = tid >> 6;
    const int wbase = wave * (RT * 16);

    const int graph = blockIdx.x / 3;
    const int term  = blockIdx.x - graph * 3;   // 0:(x,y) 1:(x,x) 2:(y,y)
    const float* xb = xg + (size_t)graph * (NPTS * DIM);
    const float* yb = yg + (size_t)graph * (NPTS * DIM);
    const float* Xp = (term == 2) ? yb : xb;
    const float* Yp = (term == 1) ? xb : yb;

    split_store(sxh, sxl, Xp, KLOG, tid);       // row side carries 1/eps scale
    split_store(syh, syl, Yp, 1.0f, tid);

    float csum;
    {
        const float hx = halfsq16(Xp + tid * DIM);
        const float hy = halfsq16(Yp + tid * DIM);
        csum = hx + hy;
        sG[NPTS + tid] = fmaf(-KLOG, hy, -10.0f);   // g_{-1} msgs -> gbuf[1]
        sF[NPTS + tid] = 0.0f;                      // finite placeholder
    }
    __syncthreads();

    u64 fmsk[RT], gmsk[RT];                      // wave-uniform tile masks
    float fsum = 0.0f, gsum = 0.0f;
    #pragma unroll 1
    for (int it = 0; it < NITERS; ++it) {
        const int cur = it & 1, alt = cur ^ 1;
        if (it < NWARM) {
            fsum = warm_pass(sxh, sxl, syh, syl, sG + alt * NPTS,
                             sF + alt * NPTS, sF + cur * NPTS,
                             sDfx + cur * 64, sDfn + cur * 64, fmsk, wbase, lane);
            gsum = warm_pass(syh, syl, sxh, sxl, sF + cur * NPTS,
                             sG + alt * NPTS, sG + cur * NPTS,
                             sDgx + cur * 64, sDgn + cur * 64, gmsk, wbase, lane);
        } else if (((it - NWARM) % 6) == 5) {    // it = 8,14: refresh
            fsum = fused_pass<false, true>(sxh, sxl, syh, syl, sG + alt * NPTS,
                              sF + alt * NPTS, sF + cur * NPTS,
                              sDgx + alt * 64, sDgn + alt * 64,
                              sDfx + cur * 64, sDfn + cur * 64,
                              nullptr, fmsk, wbase, lane);
            gsum = fused_pass<false, true>(syh, syl, sxh, sxl, sF + cur * NPTS,
                              sG + alt * NPTS, sG + cur * NPTS,
                              sDfx + cur * 64, sDfn + cur * 64,
                              sDgx + cur * 64, sDgn + cur * 64,
                              nullptr, gmsk, wbase, lane);
        } else {                                  // masked fast passes
            fsum = fused_pass<true, false>(sxh, sxl, syh, syl, sG + alt * NPTS,
                              sF + alt * NPTS, sF + cur * NPTS,
                              sDgx + alt * 64, sDgn + alt * 64,
                              sDfx + cur * 64, sDfn + cur * 64,
                              fmsk, nullptr, wbase, lane);
            gsum = fused_pass<true, false>(syh, syl, sxh, sxl, sF + cur * NPTS,
                              sG + alt * NPTS, sG + cur * NPTS,
                              sDfx + cur * 64, sDfn + cur * 64,
                              sDgx + cur * 64, sDgn + cur * 64,
                              gmsk, nullptr, wbase, lane);
        }
    }
    // final f-pass i=20 (cur=0, alt=1), masked (mask from it=14, budgeted)
    fsum = fused_pass<true, false>(sxh, sxl, syh, syl, sG + 1 * NPTS,
                      sF + 1 * NPTS, sF + 0 * NPTS,
                      sDgx + 1 * 64, sDgn + 1 * 64,
                      sDfx + 0 * 64, sDfn + 0 * 64,
                      fmsk, nullptr, wbase, lane);

    // OT = [csum - CLSE*(sum lse_f + sum lse_g)] / NPTS  (lse sums x16 dup)
    float v = fmaf(-CLSE, (fsum + gsum) * (1.0f / 16.0f), csum);
    #pragma unroll
    for (int off = 32; off; off >>= 1) v += __shfl_down(v, off, 64);
    if (lane == 0) sF[NPTS + wave] = v;          // fbuf[1] is dead
    __syncthreads();
    if (tid == 0) {
        float tot = 0.0f;
        #pragma unroll
        for (int w = 0; w < NWAVES; ++w) tot += sF[NPTS + w];
        const float wgt = ((term == 0) ? 1.0f : -0.5f)
                          / ((float)GRAPHS * (float)NPTS);
        atomicAdd(out, wgt * tot);
    }
}

extern "C" void kernel_launch(void* const* d_in, const int* in_sizes, int n_in,
                              void* d_out, int out_size, void* d_ws, size_t ws_size,
                              hipStream_t stream)
{
    (void)in_sizes; (void)n_in; (void)d_ws; (void)ws_size; (void)out_size;
    const float* x = (const float*)d_in[0];
    const float* y = (const float*)d_in[1];
    float* out = (float*)d_out;

    constexpr size_t LDSB = 4 * NPTS * DIM * sizeof(__bf16)          // 128 KiB
                          + 4 * NPTS * sizeof(float)                 //  16 KiB
                          + 8 * 64 * sizeof(float);                  //   2 KiB
    hipFuncSetAttribute((const void*)sinkhorn_kernel,
                        hipFuncAttributeMaxDynamicSharedMemorySize, (int)LDSB);

    hipMemsetAsync(out, 0, sizeof(float), stream);
    hipLaunchKernelGGL(sinkhorn_kernel, dim3(GRAPHS * 3), dim3(THREADS), LDSB,
                       stream, x, y, out);
}

// Round 21
// 1078.317 us; speedup vs baseline: 1.2401x; 1.0189x over previous
//
#include <hip/hip_runtime.h>

#define NPTS    1024
#define DIM     16
#define GRAPHS  64
#define NITERS  20
#define THREADS 1024
#define NWAVES  (THREADS / 64)
#define RT      4        // 16-row tiles per wave (16 waves x 64 rows)
#define NCHUNK  16       // 64 j-tiles, 4 per chunk
#define WINW    80.0f    // prune window, warm two-phase passes
#define WINB    30.0f    // base prune window, fused full passes
#define WREC    85.0f    // mask-record window (prune 30 + 55 stale-drift budget)
#define NWARM   3        // exact two-phase iterations before fused passes
#define REFIT   11       // single mask-refresh iteration
#define MEOCAP  100.0f   // cap on baseline drift-overshoot (exp2 range guard)

typedef __bf16 bf16x8  __attribute__((ext_vector_type(8)));
typedef __bf16 bf16x4v __attribute__((ext_vector_type(4)));
typedef float  f32x4   __attribute__((ext_vector_type(4)));
typedef unsigned long long u64;

#define KLOG 577.07801635558536f      // log2(e)/eps, eps = 0.05^2
#define CLSE 0.0017328679513998633f   // eps*ln2   (KLOG*CLSE == 1)

static __device__ __forceinline__ float fexp2(float x){ return __builtin_amdgcn_exp2f(x); }
static __device__ __forceinline__ float flog2(float x){ return __builtin_amdgcn_logf(x); }

static __device__ __forceinline__ float halfsq16(const float* p)
{
    const float4* v = (const float4*)p;
    float a = 0.0f;
    #pragma unroll
    for (int c = 0; c < 4; ++c) {
        const float4 q = v[c];
        a = fmaf(q.x, q.x, a); a = fmaf(q.y, q.y, a);
        a = fmaf(q.z, q.z, a); a = fmaf(q.w, q.w, a);
    }
    return 0.5f * a;
}

// global f32 cloud -> LDS split-bf16 (hi, lo), optionally pre-scaled
static __device__ __forceinline__ void split_store(
    __bf16* __restrict__ dh, __bf16* __restrict__ dl,
    const float* __restrict__ src, const float scale, const int tid)
{
    const float4* s4 = (const float4*)src;
    #pragma unroll 1
    for (int k = 0; k < (NPTS * DIM / 4) / THREADS; ++k) {
        const int idx = tid + k * THREADS;
        const float4 v = s4[idx];
        const float f0 = v.x * scale, f1 = v.y * scale,
                    f2 = v.z * scale, f3 = v.w * scale;
        bf16x4v h, l;
        h[0] = (__bf16)f0; l[0] = (__bf16)(f0 - (float)h[0]);
        h[1] = (__bf16)f1; l[1] = (__bf16)(f1 - (float)h[1]);
        h[2] = (__bf16)f2; l[2] = (__bf16)(f2 - (float)h[2]);
        h[3] = (__bf16)f3; l[3] = (__bf16)(f3 - (float)h[3]);
        *(bf16x4v*)(dh + idx * 4) = h;
        *(bf16x4v*)(dl + idx * 4) = l;
    }
}

static __device__ __forceinline__ void loadA(
    bf16x8 A[RT], const __bf16* __restrict__ rH, const __bf16* __restrict__ rL,
    const int wbase, const int lane)
{
    const int g = lane >> 4, n = lane & 15, gh = g & 1;
    const __bf16* ap = (g < 2 ? rH : rL) + (wbase + n) * DIM + gh * 8;
    #pragma unroll
    for (int rt = 0; rt < RT; ++rt)
        A[rt] = *(const bf16x8*)(ap + rt * (16 * DIM));
}

// Full pruned exp-sum sweep over all 64 j-tiles, 3-deep MFMA rotation.
// Optionally RECORDs the active-tile bitmask (h > -WREC).
template<bool RECORD>
static __device__ __forceinline__ void sweep_sum_full(
    const bf16x8 A[RT], const __bf16* __restrict__ b1p,
    const __bf16* __restrict__ b2p, const float* __restrict__ tp,
    const float me[RT][4], const float win, float s[RT][4],
    u64* __restrict__ rec)
{
    if constexpr (RECORD) {
        #pragma unroll
        for (int r = 0; r < RT; ++r) rec[r] = 0ull;
    }
    #pragma unroll 1
    for (int c = 0; c < NCHUNK; ++c) {
        const int off = c * (4 * 16 * DIM);
        float t[4]; bf16x8 B1[4], B2[4];
        #pragma unroll
        for (int q = 0; q < 4; ++q) {
            t[q]  = tp[c * 64 + q * 16];
            B1[q] = *(const bf16x8*)(b1p + off + q * (16 * DIM));
            B2[q] = *(const bf16x8*)(b2p + off + q * (16 * DIM));
        }
        f32x4 w[3];
        #define ISSUE(kk, slot) do {                                          \
            const int q_ = (kk) >> 2, r_ = (kk) & 3;                          \
            f32x4 a_ = { t[q_] - me[r_][0], t[q_] - me[r_][1],                \
                         t[q_] - me[r_][2], t[q_] - me[r_][3] };              \
            a_ = __builtin_amdgcn_mfma_f32_16x16x32_bf16(A[r_], B2[q_], a_, 0, 0, 0); \
            w[slot] = __builtin_amdgcn_mfma_f32_16x16x32_bf16(A[r_], B1[q_], a_, 0, 0, 0); \
        } while (0)
        ISSUE(0, 0); ISSUE(1, 1);
        #pragma unroll
        for (int k = 0; k < 16; ++k) {
            if (k < 14) ISSUE(k + 2, (k + 2) % 3);
            const f32x4 wc = w[k % 3];
            const int rt = k & 3;
            const float h = fmaxf(fmaxf(wc[0], wc[1]), fmaxf(wc[2], wc[3]));
            if constexpr (RECORD) {
                if (__any(h > -WREC))
                    rec[rt] |= 1ull << (c * 4 + (k >> 2));
            }
            if (__any(h > -win)) {
                s[rt][0] += fexp2(wc[0]);
                s[rt][1] += fexp2(wc[1]);
                s[rt][2] += fexp2(wc[2]);
                s[rt][3] += fexp2(wc[3]);
            }
        }
        #undef ISSUE
    }
}

// Masked sweep: per row-tile (static rt), walk the set bits of its mask in
// pairs with 2-deep MFMA rotation (tile b1's MFMAs hide tile b0's latency).
// No per-tile prune re-check: recorded tiles always exp2 (sub-window terms
// underflow to 0 harmlessly). Mask bits are wave-uniform -> scalar branches.
static __device__ __forceinline__ void sweep_sum_masked(
    const bf16x8 A[RT], const __bf16* __restrict__ b1p,
    const __bf16* __restrict__ b2p, const float* __restrict__ tp,
    const float me[RT][4], float s[RT][4], const u64* __restrict__ msk)
{
    #pragma unroll
    for (int rt = 0; rt < RT; ++rt) {
        const float me0 = me[rt][0], me1 = me[rt][1],
                    me2 = me[rt][2], me3 = me[rt][3];
        float s0 = 0.0f, s1 = 0.0f, s2 = 0.0f, s3 = 0.0f;
        u64 bits = msk[rt];
        #pragma unroll 1
        while (bits) {
            const int b0 = (int)__builtin_ctzll(bits); bits &= bits - 1;
            const float t0 = tp[b0 * 16];
            f32x4 w0 = { t0 - me0, t0 - me1, t0 - me2, t0 - me3 };
            w0 = __builtin_amdgcn_mfma_f32_16x16x32_bf16(
                     A[rt], *(const bf16x8*)(b2p + b0 * 256), w0, 0, 0, 0);
            w0 = __builtin_amdgcn_mfma_f32_16x16x32_bf16(
                     A[rt], *(const bf16x8*)(b1p + b0 * 256), w0, 0, 0, 0);
            const bool has1 = (bits != 0ull);
            f32x4 w1;
            if (has1) {
                const int b1 = (int)__builtin_ctzll(bits); bits &= bits - 1;
                const float t1 = tp[b1 * 16];
                f32x4 a1 = { t1 - me0, t1 - me1, t1 - me2, t1 - me3 };
                a1 = __builtin_amdgcn_mfma_f32_16x16x32_bf16(
                         A[rt], *(const bf16x8*)(b2p + b1 * 256), a1, 0, 0, 0);
                w1 = __builtin_amdgcn_mfma_f32_16x16x32_bf16(
                         A[rt], *(const bf16x8*)(b1p + b1 * 256), a1, 0, 0, 0);
            }
            s0 += fexp2(w0[0]); s1 += fexp2(w0[1]);
            s2 += fexp2(w0[2]); s3 += fexp2(w0[3]);
            if (has1) {
                s0 += fexp2(w1[0]); s1 += fexp2(w1[1]);
                s2 += fexp2(w1[2]); s3 += fexp2(w1[3]);
            }
        }
        s[rt][0] += s0; s[rt][1] += s1; s[rt][2] += s2; s[rt][3] += s3;
    }
}

// Publish epilogue: n==0 lanes write fresh messages (bNew != any buffer read
// this pass) + drift partials vs bOld, then ONE barrier makes all visible.
static __device__ __forceinline__ void publish(
    const float lse[RT][4], const float* __restrict__ bOld,
    float* __restrict__ bNew, float* __restrict__ dOutX,
    float* __restrict__ dOutN, const int wbase, const int lane)
{
    const int g = lane >> 4, n = lane & 15;
    if (n == 0) {
        float dmx = -3.0e38f, dmn = 3.0e38f;
        #pragma unroll
        for (int rt = 0; rt < RT; ++rt) {
            const int row4 = wbase + rt * 16 + g * 4;
            const f32x4 old = *(const f32x4*)(bOld + row4);
            f32x4 mv;
            #pragma unroll
            for (int e = 0; e < 4; ++e) {
                mv[e] = -10.0f - lse[rt][e];
                const float d = mv[e] - old[e];
                dmx = fmaxf(dmx, d); dmn = fminf(dmn, d);
            }
            *(f32x4*)(bNew + row4) = mv;
        }
        dOutX[(wbase >> 4) + g] = dmx;
        dOutN[(wbase >> 4) + g] = dmn;
    }
    __syncthreads();
}

// Warm half-iteration: exact two-phase (max sweep + pruned sum); records mask.
static __device__ __forceinline__ float warm_pass(
    const __bf16* __restrict__ rH, const __bf16* __restrict__ rL,
    const __bf16* __restrict__ cH, const __bf16* __restrict__ cL,
    const float* __restrict__ tOld, const float* __restrict__ bOld,
    float* __restrict__ bNew, float* __restrict__ dOutX,
    float* __restrict__ dOutN, u64* __restrict__ rec,
    const int wbase, const int lane)
{
    const int g = lane >> 4, n = lane & 15, gh = g & 1;
    bf16x8 A[RT];
    loadA(A, rH, rL, wbase, lane);
    const __bf16* b1p = cH + n * DIM + gh * 8;
    const __bf16* b2p = cL + n * DIM + gh * 8;
    const float*  tp  = tOld + n;

    // pass 1: approx row maxima (B = hi only, 2-deep rotation)
    float m[RT][4];
    #pragma unroll
    for (int rt = 0; rt < RT; ++rt)
        #pragma unroll
        for (int e = 0; e < 4; ++e) m[rt][e] = -3.0e38f;

    #pragma unroll 1
    for (int c = 0; c < NCHUNK; ++c) {
        const int off = c * (4 * 16 * DIM);
        float t[4]; bf16x8 B[4];
        #pragma unroll
        for (int q = 0; q < 4; ++q) {
            t[q] = tp[c * 64 + q * 16];
            B[q] = *(const bf16x8*)(b1p + off + q * (16 * DIM));
        }
        f32x4 w[2];
        {
            f32x4 a0 = { t[0], t[0], t[0], t[0] };
            w[0] = __builtin_amdgcn_mfma_f32_16x16x32_bf16(A[0], B[0], a0, 0, 0, 0);
        }
        #pragma unroll
        for (int k = 0; k < 16; ++k) {
            if (k < 15) {
                const int kn = k + 1, qn = kn >> 2, rn = kn & 3;
                f32x4 a = { t[qn], t[qn], t[qn], t[qn] };
                w[kn & 1] = __builtin_amdgcn_mfma_f32_16x16x32_bf16(A[rn], B[qn], a, 0, 0, 0);
            }
            const f32x4 wc = w[k & 1];
            const int rt = k & 3;
            m[rt][0] = fmaxf(m[rt][0], wc[0]);
            m[rt][1] = fmaxf(m[rt][1], wc[1]);
            m[rt][2] = fmaxf(m[rt][2], wc[2]);
            m[rt][3] = fmaxf(m[rt][3], wc[3]);
        }
    }
    #pragma unroll
    for (int rt = 0; rt < RT; ++rt)
        #pragma unroll
        for (int e = 0; e < 4; ++e) {
            float mm = m[rt][e];
            #pragma unroll
            for (int d = 1; d < 16; d <<= 1)
                mm = fmaxf(mm, __shfl_xor(mm, d, 64));
            m[rt][e] = mm;
        }

    // pass 2: pruned exp-sums + mask record
    float s[RT][4];
    #pragma unroll
    for (int rt = 0; rt < RT; ++rt)
        #pragma unroll
        for (int e = 0; e < 4; ++e) s[rt][e] = 0.0f;
    sweep_sum_full<true>(A, b1p, b2p, tp, m, WINW, s, rec);

    float lsum = 0.0f;
    float lse[RT][4];
    #pragma unroll
    for (int rt = 0; rt < RT; ++rt)
        #pragma unroll
        for (int e = 0; e < 4; ++e) {
            float ss = s[rt][e];
            #pragma unroll
            for (int d = 1; d < 16; d <<= 1)
                ss += __shfl_xor(ss, d, 64);
            ss = fmaxf(ss, 1.0e-30f);
            const float l = m[rt][e] + flog2(ss);
            lsum += l;
            lse[rt][e] = l;
        }
    publish(lse, bOld, bNew, dOutX, dOutN, wbase, lane);
    return lsum;
}

// Fused half-iteration: single sweep; me = lse_prev + min(maxDrift, MEOCAP)
// (inductive upper bound on the true row max; cap guards exp2 range —
// active only pre-convergence, which NWARM covers). MASKED walks recorded-
// active tiles only; RECORD refreshes the mask during a full sweep.
template<bool MASKED, bool RECORD>
static __device__ __forceinline__ float fused_pass(
    const __bf16* __restrict__ rH, const __bf16* __restrict__ rL,
    const __bf16* __restrict__ cH, const __bf16* __restrict__ cL,
    const float* __restrict__ tOld, const float* __restrict__ bOld,
    float* __restrict__ bNew,
    const float* __restrict__ dInX, const float* __restrict__ dInN,
    float* __restrict__ dOutX, float* __restrict__ dOutN,
    const u64* __restrict__ msk, u64* __restrict__ rec,
    const int wbase, const int lane)
{
    const int g = lane >> 4, n = lane & 15, gh = g & 1;
    bf16x8 A[RT];
    loadA(A, rH, rL, wbase, lane);

    // drift of the opposite-side messages from the preceding pass
    float dmx = dInX[lane], dmn = dInN[lane];
    #pragma unroll
    for (int d = 1; d < 64; d <<= 1) {
        dmx = fmaxf(dmx, __shfl_xor(dmx, d, 64));
        dmn = fminf(dmn, __shfl_xor(dmn, d, 64));
    }
    const float win  = WINB + fmaxf(0.0f, dmx - dmn);
    const float dmxc = fminf(dmx, MEOCAP);       // exp2-range guard

    float me[RT][4], s[RT][4];
    #pragma unroll
    for (int rt = 0; rt < RT; ++rt) {
        const f32x4 v = *(const f32x4*)(bOld + wbase + rt * 16 + g * 4);
        #pragma unroll
        for (int e = 0; e < 4; ++e) {
            me[rt][e] = (-10.0f - v[e]) + dmxc;  // lse_prev + drift bound
            s[rt][e]  = 0.0f;
        }
    }

    const __bf16* b1p = cH + n * DIM + gh * 8;
    const __bf16* b2p = cL + n * DIM + gh * 8;
    if constexpr (MASKED)
        sweep_sum_masked(A, b1p, b2p, tOld + n, me, s, msk);
    else
        sweep_sum_full<RECORD>(A, b1p, b2p, tOld + n, me, win, s, rec);

    float lsum = 0.0f;
    float lse[RT][4];
    #pragma unroll
    for (int rt = 0; rt < RT; ++rt)
        #pragma unroll
        for (int e = 0; e < 4; ++e) {
            float ss = s[rt][e];
            #pragma unroll
            for (int d = 1; d < 16; d <<= 1)
                ss += __shfl_xor(ss, d, 64);
            ss = fmaxf(ss, 1.0e-30f);
            const float l = me[rt][e] + flog2(ss);
            lsum += l;
            lse[rt][e] = l;
        }
    publish(lse, bOld, bNew, dOutX, dOutN, wbase, lane);
    return lsum;
}

__global__ __launch_bounds__(THREADS)
void sinkhorn_kernel(const float* __restrict__ xg,
                     const float* __restrict__ yg,
                     float* __restrict__ out)
{
    extern __shared__ char ldsraw[];
    __bf16* sxh = (__bf16*)ldsraw;              // [1024][16] hi of K*x
    __bf16* sxl = sxh + NPTS * DIM;
    __bf16* syh = sxl + NPTS * DIM;
    __bf16* syl = syh + NPTS * DIM;
    float*  sF  = (float*)(syl + NPTS * DIM);   // [2][1024] f-messages
    float*  sG  = sF + 2 * NPTS;                // [2][1024] g-messages
    float*  sDfx = sG + 2 * NPTS;               // [2][64] f-drift max
    float*  sDfn = sDfx + 2 * 64;               // [2][64] f-drift min
    float*  sDgx = sDfn + 2 * 64;               // [2][64] g-drift max
    float*  sDgn = sDgx + 2 * 64;               // [2][64] g-drift min

    const int tid   = threadIdx.x;
    const int lane  = tid & 63;
    const int wave  = tid >> 6;
    const int wbase = wave * (RT * 16);

    const int graph = blockIdx.x / 3;
    const int term  = blockIdx.x - graph * 3;   // 0:(x,y) 1:(x,x) 2:(y,y)
    const float* xb = xg + (size_t)graph * (NPTS * DIM);
    const float* yb = yg + (size_t)graph * (NPTS * DIM);
    const float* Xp = (term == 2) ? yb : xb;
    const float* Yp = (term == 1) ? xb : yb;

    split_store(sxh, sxl, Xp, KLOG, tid);       // row side carries 1/eps scale
    split_store(syh, syl, Yp, 1.0f, tid);

    float csum;
    {
        const float hx = halfsq16(Xp + tid * DIM);
        const float hy = halfsq16(Yp + tid * DIM);
        csum = hx + hy;
        sG[NPTS + tid] = fmaf(-KLOG, hy, -10.0f);   // g_{-1} msgs -> gbuf[1]
        sF[NPTS + tid] = 0.0f;                      // finite placeholder
    }
    __syncthreads();

    u64 fmsk[RT], gmsk[RT];                      // wave-uniform tile masks
    float fsum = 0.0f, gsum = 0.0f;
    #pragma unroll 1
    for (int it = 0; it < NITERS; ++it) {
        const int cur = it & 1, alt = cur ^ 1;
        if (it < NWARM) {
            fsum = warm_pass(sxh, sxl, syh, syl, sG + alt * NPTS,
                             sF + alt * NPTS, sF + cur * NPTS,
                             sDfx + cur * 64, sDfn + cur * 64, fmsk, wbase, lane);
            gsum = warm_pass(syh, syl, sxh, sxl, sF + cur * NPTS,
                             sG + alt * NPTS, sG + cur * NPTS,
                             sDgx + cur * 64, sDgn + cur * 64, gmsk, wbase, lane);
        } else if (it == REFIT) {                // single mask refresh
            fsum = fused_pass<false, true>(sxh, sxl, syh, syl, sG + alt * NPTS,
                              sF + alt * NPTS, sF + cur * NPTS,
                              sDgx + alt * 64, sDgn + alt * 64,
                              sDfx + cur * 64, sDfn + cur * 64,
                              nullptr, fmsk, wbase, lane);
            gsum = fused_pass<false, true>(syh, syl, sxh, sxl, sF + cur * NPTS,
                              sG + alt * NPTS, sG + cur * NPTS,
                              sDfx + cur * 64, sDfn + cur * 64,
                              sDgx + cur * 64, sDgn + cur * 64,
                              nullptr, gmsk, wbase, lane);
        } else {                                  // masked fast passes
            fsum = fused_pass<true, false>(sxh, sxl, syh, syl, sG + alt * NPTS,
                              sF + alt * NPTS, sF + cur * NPTS,
                              sDgx + alt * 64, sDgn + alt * 64,
                              sDfx + cur * 64, sDfn + cur * 64,
                              fmsk, nullptr, wbase, lane);
            gsum = fused_pass<true, false>(syh, syl, sxh, sxl, sF + cur * NPTS,
                              sG + alt * NPTS, sG + cur * NPTS,
                              sDfx + cur * 64, sDfn + cur * 64,
                              sDgx + cur * 64, sDgn + cur * 64,
                              gmsk, nullptr, wbase, lane);
        }
    }
    // final f-pass i=20 (cur=0, alt=1), masked (mask from it=11, budgeted)
    fsum = fused_pass<true, false>(sxh, sxl, syh, syl, sG + 1 * NPTS,
                      sF + 1 * NPTS, sF + 0 * NPTS,
                      sDgx + 1 * 64, sDgn + 1 * 64,
                      sDfx + 0 * 64, sDfn + 0 * 64,
                      fmsk, nullptr, wbase, lane);

    // OT = [csum - CLSE*(sum lse_f + sum lse_g)] / NPTS  (lse sums x16 dup)
    float v = fmaf(-CLSE, (fsum + gsum) * (1.0f / 16.0f), csum);
    #pragma unroll
    for (int off = 32; off; off >>= 1) v += __shfl_down(v, off, 64);
    if (lane == 0) sF[NPTS + wave] = v;          // fbuf[1] is dead
    __syncthreads();
    if (tid == 0) {
        float tot = 0.0f;
        #pragma unroll
        for (int w = 0; w < NWAVES; ++w) tot += sF[NPTS + w];
        const float wgt = ((term == 0) ? 1.0f : -0.5f)
                          / ((float)GRAPHS * (float)NPTS);
        atomicAdd(out, wgt * tot);
    }
}

extern "C" void kernel_launch(void* const* d_in, const int* in_sizes, int n_in,
                              void* d_out, int out_size, void* d_ws, size_t ws_size,
                              hipStream_t stream)
{
    (void)in_sizes; (void)n_in; (void)d_ws; (void)ws_size; (void)out_size;
    const float* x = (const float*)d_in[0];
    const float* y = (const float*)d_in[1];
    float* out = (float*)d_out;

    constexpr size_t LDSB = 4 * NPTS * DIM * sizeof(__bf16)          // 128 KiB
                          + 4 * NPTS * sizeof(float)                 //  16 KiB
                          + 8 * 64 * sizeof(float);                  //   2 KiB
    hipFuncSetAttribute((const void*)sinkhorn_kernel,
                        hipFuncAttributeMaxDynamicSharedMemorySize, (int)LDSB);

    hipMemsetAsync(out, 0, sizeof(float), stream);
    hipLaunchKernelGGL(sinkhorn_kernel, dim3(GRAPHS * 3), dim3(THREADS), LDSB,
                       stream, x, y, out);
}

// Round 22
// 1056.323 us; speedup vs baseline: 1.2659x; 1.0208x over previous
//
#include <hip/hip_runtime.h>

#define NPTS    1024
#define DIM     16
#define GRAPHS  64
#define NITERS  20
#define THREADS 1024
#define NWAVES  (THREADS / 64)
#define RT      4        // 16-row tiles per wave (16 waves x 64 rows)
#define NCHUNK  16       // 64 j-tiles, 4 per chunk
#define WINW    80.0f    // prune window, warm two-phase passes
#define WINB    30.0f    // base prune window, fused full passes
#define WREC    85.0f    // mask-record window (prune 30 + 55 stale-drift budget)
#define NWARM   2        // exact two-phase iterations before fused passes
#define MEOCAP  100.0f   // cap on baseline drift-overshoot (exp2 range guard)

typedef __bf16 bf16x8  __attribute__((ext_vector_type(8)));
typedef __bf16 bf16x4v __attribute__((ext_vector_type(4)));
typedef float  f32x4   __attribute__((ext_vector_type(4)));
typedef unsigned long long u64;

#define KLOG 577.07801635558536f      // log2(e)/eps, eps = 0.05^2
#define CLSE 0.0017328679513998633f   // eps*ln2   (KLOG*CLSE == 1)

static __device__ __forceinline__ float fexp2(float x){ return __builtin_amdgcn_exp2f(x); }
static __device__ __forceinline__ float flog2(float x){ return __builtin_amdgcn_logf(x); }

static __device__ __forceinline__ float halfsq16(const float* p)
{
    const float4* v = (const float4*)p;
    float a = 0.0f;
    #pragma unroll
    for (int c = 0; c < 4; ++c) {
        const float4 q = v[c];
        a = fmaf(q.x, q.x, a); a = fmaf(q.y, q.y, a);
        a = fmaf(q.z, q.z, a); a = fmaf(q.w, q.w, a);
    }
    return 0.5f * a;
}

// global f32 cloud -> LDS split-bf16 (hi, lo), optionally pre-scaled
static __device__ __forceinline__ void split_store(
    __bf16* __restrict__ dh, __bf16* __restrict__ dl,
    const float* __restrict__ src, const float scale, const int tid)
{
    const float4* s4 = (const float4*)src;
    #pragma unroll 1
    for (int k = 0; k < (NPTS * DIM / 4) / THREADS; ++k) {
        const int idx = tid + k * THREADS;
        const float4 v = s4[idx];
        const float f0 = v.x * scale, f1 = v.y * scale,
                    f2 = v.z * scale, f3 = v.w * scale;
        bf16x4v h, l;
        h[0] = (__bf16)f0; l[0] = (__bf16)(f0 - (float)h[0]);
        h[1] = (__bf16)f1; l[1] = (__bf16)(f1 - (float)h[1]);
        h[2] = (__bf16)f2; l[2] = (__bf16)(f2 - (float)h[2]);
        h[3] = (__bf16)f3; l[3] = (__bf16)(f3 - (float)h[3]);
        *(bf16x4v*)(dh + idx * 4) = h;
        *(bf16x4v*)(dl + idx * 4) = l;
    }
}

static __device__ __forceinline__ void loadA(
    bf16x8 A[RT], const __bf16* __restrict__ rH, const __bf16* __restrict__ rL,
    const int wbase, const int lane)
{
    const int g = lane >> 4, n = lane & 15, gh = g & 1;
    const __bf16* ap = (g < 2 ? rH : rL) + (wbase + n) * DIM + gh * 8;
    #pragma unroll
    for (int rt = 0; rt < RT; ++rt)
        A[rt] = *(const bf16x8*)(ap + rt * (16 * DIM));
}

// Full pruned exp-sum sweep over all 64 j-tiles, 3-deep MFMA rotation.
// Optionally RECORDs the active-tile bitmask (h > -WREC).
template<bool RECORD>
static __device__ __forceinline__ void sweep_sum_full(
    const bf16x8 A[RT], const __bf16* __restrict__ b1p,
    const __bf16* __restrict__ b2p, const float* __restrict__ tp,
    const float me[RT][4], const float win, float s[RT][4],
    u64* __restrict__ rec)
{
    if constexpr (RECORD) {
        #pragma unroll
        for (int r = 0; r < RT; ++r) rec[r] = 0ull;
    }
    #pragma unroll 1
    for (int c = 0; c < NCHUNK; ++c) {
        const int off = c * (4 * 16 * DIM);
        float t[4]; bf16x8 B1[4], B2[4];
        #pragma unroll
        for (int q = 0; q < 4; ++q) {
            t[q]  = tp[c * 64 + q * 16];
            B1[q] = *(const bf16x8*)(b1p + off + q * (16 * DIM));
            B2[q] = *(const bf16x8*)(b2p + off + q * (16 * DIM));
        }
        f32x4 w[3];
        #define ISSUE(kk, slot) do {                                          \
            const int q_ = (kk) >> 2, r_ = (kk) & 3;                          \
            f32x4 a_ = { t[q_] - me[r_][0], t[q_] - me[r_][1],                \
                         t[q_] - me[r_][2], t[q_] - me[r_][3] };              \
            a_ = __builtin_amdgcn_mfma_f32_16x16x32_bf16(A[r_], B2[q_], a_, 0, 0, 0); \
            w[slot] = __builtin_amdgcn_mfma_f32_16x16x32_bf16(A[r_], B1[q_], a_, 0, 0, 0); \
        } while (0)
        ISSUE(0, 0); ISSUE(1, 1);
        #pragma unroll
        for (int k = 0; k < 16; ++k) {
            if (k < 14) ISSUE(k + 2, (k + 2) % 3);
            const f32x4 wc = w[k % 3];
            const int rt = k & 3;
            const float h = fmaxf(fmaxf(wc[0], wc[1]), fmaxf(wc[2], wc[3]));
            if constexpr (RECORD) {
                if (__any(h > -WREC))
                    rec[rt] |= 1ull << (c * 4 + (k >> 2));
            }
            if (__any(h > -win)) {
                s[rt][0] += fexp2(wc[0]);
                s[rt][1] += fexp2(wc[1]);
                s[rt][2] += fexp2(wc[2]);
                s[rt][3] += fexp2(wc[3]);
            }
        }
        #undef ISSUE
    }
}

// Masked sweep: per row-tile (static rt), walk the set bits of its mask in
// pairs with 2-deep MFMA rotation (tile b1's MFMAs hide tile b0's latency).
// No per-tile prune re-check: recorded tiles always exp2 (sub-window terms
// underflow to 0 harmlessly). Mask bits are wave-uniform -> scalar branches.
static __device__ __forceinline__ void sweep_sum_masked(
    const bf16x8 A[RT], const __bf16* __restrict__ b1p,
    const __bf16* __restrict__ b2p, const float* __restrict__ tp,
    const float me[RT][4], float s[RT][4], const u64* __restrict__ msk)
{
    #pragma unroll
    for (int rt = 0; rt < RT; ++rt) {
        const float me0 = me[rt][0], me1 = me[rt][1],
                    me2 = me[rt][2], me3 = me[rt][3];
        float s0 = 0.0f, s1 = 0.0f, s2 = 0.0f, s3 = 0.0f;
        u64 bits = msk[rt];
        #pragma unroll 1
        while (bits) {
            const int b0 = (int)__builtin_ctzll(bits); bits &= bits - 1;
            const float t0 = tp[b0 * 16];
            f32x4 w0 = { t0 - me0, t0 - me1, t0 - me2, t0 - me3 };
            w0 = __builtin_amdgcn_mfma_f32_16x16x32_bf16(
                     A[rt], *(const bf16x8*)(b2p + b0 * 256), w0, 0, 0, 0);
            w0 = __builtin_amdgcn_mfma_f32_16x16x32_bf16(
                     A[rt], *(const bf16x8*)(b1p + b0 * 256), w0, 0, 0, 0);
            const bool has1 = (bits != 0ull);
            f32x4 w1;
            if (has1) {
                const int b1 = (int)__builtin_ctzll(bits); bits &= bits - 1;
                const float t1 = tp[b1 * 16];
                f32x4 a1 = { t1 - me0, t1 - me1, t1 - me2, t1 - me3 };
                a1 = __builtin_amdgcn_mfma_f32_16x16x32_bf16(
                         A[rt], *(const bf16x8*)(b2p + b1 * 256), a1, 0, 0, 0);
                w1 = __builtin_amdgcn_mfma_f32_16x16x32_bf16(
                         A[rt], *(const bf16x8*)(b1p + b1 * 256), a1, 0, 0, 0);
            }
            s0 += fexp2(w0[0]); s1 += fexp2(w0[1]);
            s2 += fexp2(w0[2]); s3 += fexp2(w0[3]);
            if (has1) {
                s0 += fexp2(w1[0]); s1 += fexp2(w1[1]);
                s2 += fexp2(w1[2]); s3 += fexp2(w1[3]);
            }
        }
        s[rt][0] += s0; s[rt][1] += s1; s[rt][2] += s2; s[rt][3] += s3;
    }
}

// Publish epilogue: n==0 lanes write fresh messages (bNew != any buffer read
// this pass) + drift partials vs bOld, then ONE barrier makes all visible.
static __device__ __forceinline__ void publish(
    const float lse[RT][4], const float* __restrict__ bOld,
    float* __restrict__ bNew, float* __restrict__ dOutX,
    float* __restrict__ dOutN, const int wbase, const int lane)
{
    const int g = lane >> 4, n = lane & 15;
    if (n == 0) {
        float dmx = -3.0e38f, dmn = 3.0e38f;
        #pragma unroll
        for (int rt = 0; rt < RT; ++rt) {
            const int row4 = wbase + rt * 16 + g * 4;
            const f32x4 old = *(const f32x4*)(bOld + row4);
            f32x4 mv;
            #pragma unroll
            for (int e = 0; e < 4; ++e) {
                mv[e] = -10.0f - lse[rt][e];
                const float d = mv[e] - old[e];
                dmx = fmaxf(dmx, d); dmn = fminf(dmn, d);
            }
            *(f32x4*)(bNew + row4) = mv;
        }
        dOutX[(wbase >> 4) + g] = dmx;
        dOutN[(wbase >> 4) + g] = dmn;
    }
    __syncthreads();
}

// Warm half-iteration: exact two-phase (max sweep + pruned sum); records mask.
static __device__ __forceinline__ float warm_pass(
    const __bf16* __restrict__ rH, const __bf16* __restrict__ rL,
    const __bf16* __restrict__ cH, const __bf16* __restrict__ cL,
    const float* __restrict__ tOld, const float* __restrict__ bOld,
    float* __restrict__ bNew, float* __restrict__ dOutX,
    float* __restrict__ dOutN, u64* __restrict__ rec,
    const int wbase, const int lane)
{
    const int g = lane >> 4, n = lane & 15, gh = g & 1;
    bf16x8 A[RT];
    loadA(A, rH, rL, wbase, lane);
    const __bf16* b1p = cH + n * DIM + gh * 8;
    const __bf16* b2p = cL + n * DIM + gh * 8;
    const float*  tp  = tOld + n;

    // pass 1: approx row maxima (B = hi only, 2-deep rotation)
    float m[RT][4];
    #pragma unroll
    for (int rt = 0; rt < RT; ++rt)
        #pragma unroll
        for (int e = 0; e < 4; ++e) m[rt][e] = -3.0e38f;

    #pragma unroll 1
    for (int c = 0; c < NCHUNK; ++c) {
        const int off = c * (4 * 16 * DIM);
        float t[4]; bf16x8 B[4];
        #pragma unroll
        for (int q = 0; q < 4; ++q) {
            t[q] = tp[c * 64 + q * 16];
            B[q] = *(const bf16x8*)(b1p + off + q * (16 * DIM));
        }
        f32x4 w[2];
        {
            f32x4 a0 = { t[0], t[0], t[0], t[0] };
            w[0] = __builtin_amdgcn_mfma_f32_16x16x32_bf16(A[0], B[0], a0, 0, 0, 0);
        }
        #pragma unroll
        for (int k = 0; k < 16; ++k) {
            if (k < 15) {
                const int kn = k + 1, qn = kn >> 2, rn = kn & 3;
                f32x4 a = { t[qn], t[qn], t[qn], t[qn] };
                w[kn & 1] = __builtin_amdgcn_mfma_f32_16x16x32_bf16(A[rn], B[qn], a, 0, 0, 0);
            }
            const f32x4 wc = w[k & 1];
            const int rt = k & 3;
            m[rt][0] = fmaxf(m[rt][0], wc[0]);
            m[rt][1] = fmaxf(m[rt][1], wc[1]);
            m[rt][2] = fmaxf(m[rt][2], wc[2]);
            m[rt][3] = fmaxf(m[rt][3], wc[3]);
        }
    }
    #pragma unroll
    for (int rt = 0; rt < RT; ++rt)
        #pragma unroll
        for (int e = 0; e < 4; ++e) {
            float mm = m[rt][e];
            #pragma unroll
            for (int d = 1; d < 16; d <<= 1)
                mm = fmaxf(mm, __shfl_xor(mm, d, 64));
            m[rt][e] = mm;
        }

    // pass 2: pruned exp-sums + mask record
    float s[RT][4];
    #pragma unroll
    for (int rt = 0; rt < RT; ++rt)
        #pragma unroll
        for (int e = 0; e < 4; ++e) s[rt][e] = 0.0f;
    sweep_sum_full<true>(A, b1p, b2p, tp, m, WINW, s, rec);

    float lsum = 0.0f;
    float lse[RT][4];
    #pragma unroll
    for (int rt = 0; rt < RT; ++rt)
        #pragma unroll
        for (int e = 0; e < 4; ++e) {
            float ss = s[rt][e];
            #pragma unroll
            for (int d = 1; d < 16; d <<= 1)
                ss += __shfl_xor(ss, d, 64);
            ss = fmaxf(ss, 1.0e-30f);
            const float l = m[rt][e] + flog2(ss);
            lsum += l;
            lse[rt][e] = l;
        }
    publish(lse, bOld, bNew, dOutX, dOutN, wbase, lane);
    return lsum;
}

// Fused half-iteration: single sweep; me = lse_prev + min(maxDrift, MEOCAP).
// LSE shift identity is exact for any me absent fp32 range issues; the cap
// bounds overshoot <= ~110 (< 126 underflow) and undershoot overflows only
// for drift > ~230 (not seen past iteration 1). MASKED walks recorded-
// active tiles only; RECORD refreshes the mask during a full sweep.
template<bool MASKED, bool RECORD>
static __device__ __forceinline__ float fused_pass(
    const __bf16* __restrict__ rH, const __bf16* __restrict__ rL,
    const __bf16* __restrict__ cH, const __bf16* __restrict__ cL,
    const float* __restrict__ tOld, const float* __restrict__ bOld,
    float* __restrict__ bNew,
    const float* __restrict__ dInX, const float* __restrict__ dInN,
    float* __restrict__ dOutX, float* __restrict__ dOutN,
    const u64* __restrict__ msk, u64* __restrict__ rec,
    const int wbase, const int lane)
{
    const int g = lane >> 4, n = lane & 15, gh = g & 1;
    bf16x8 A[RT];
    loadA(A, rH, rL, wbase, lane);

    // drift of the opposite-side messages from the preceding pass
    float dmx = dInX[lane], dmn = dInN[lane];
    #pragma unroll
    for (int d = 1; d < 64; d <<= 1) {
        dmx = fmaxf(dmx, __shfl_xor(dmx, d, 64));
        dmn = fminf(dmn, __shfl_xor(dmn, d, 64));
    }
    const float win  = WINB + fmaxf(0.0f, dmx - dmn);
    const float dmxc = fminf(dmx, MEOCAP);       // exp2-range guard

    float me[RT][4], s[RT][4];
    #pragma unroll
    for (int rt = 0; rt < RT; ++rt) {
        const f32x4 v = *(const f32x4*)(bOld + wbase + rt * 16 + g * 4);
        #pragma unroll
        for (int e = 0; e < 4; ++e) {
            me[rt][e] = (-10.0f - v[e]) + dmxc;  // lse_prev + drift bound
            s[rt][e]  = 0.0f;
        }
    }

    const __bf16* b1p = cH + n * DIM + gh * 8;
    const __bf16* b2p = cL + n * DIM + gh * 8;
    if constexpr (MASKED)
        sweep_sum_masked(A, b1p, b2p, tOld + n, me, s, msk);
    else
        sweep_sum_full<RECORD>(A, b1p, b2p, tOld + n, me, win, s, rec);

    float lsum = 0.0f;
    float lse[RT][4];
    #pragma unroll
    for (int rt = 0; rt < RT; ++rt)
        #pragma unroll
        for (int e = 0; e < 4; ++e) {
            float ss = (s[rt][e] > 1.0e-30f) ? s[rt][e] : 1.0e-30f;
            #pragma unroll
            for (int d = 1; d < 16; d <<= 1)
                ss += __shfl_xor(ss, d, 64);
            const float l = me[rt][e] + flog2(ss);
            lsum += l;
            lse[rt][e] = l;
        }
    publish(lse, bOld, bNew, dOutX, dOutN, wbase, lane);
    return lsum;
}

__global__ __launch_bounds__(THREADS)
void sinkhorn_kernel(const float* __restrict__ xg,
                     const float* __restrict__ yg,
                     float* __restrict__ out)
{
    extern __shared__ char ldsraw[];
    __bf16* sxh = (__bf16*)ldsraw;              // [1024][16] hi of K*x
    __bf16* sxl = sxh + NPTS * DIM;
    __bf16* syh = sxl + NPTS * DIM;
    __bf16* syl = syh + NPTS * DIM;
    float*  sF  = (float*)(syl + NPTS * DIM);   // [2][1024] f-messages
    float*  sG  = sF + 2 * NPTS;                // [2][1024] g-messages
    float*  sDfx = sG + 2 * NPTS;               // [2][64] f-drift max
    float*  sDfn = sDfx + 2 * 64;               // [2][64] f-drift min
    float*  sDgx = sDfn + 2 * 64;               // [2][64] g-drift max
    float*  sDgn = sDgx + 2 * 64;               // [2][64] g-drift min

    const int tid   = threadIdx.x;
    const int lane  = tid & 63;
    const int wave  = tid >> 6;
    const int wbase = wave * (RT * 16);

    const int graph = blockIdx.x / 3;
    const int term  = blockIdx.x - graph * 3;   // 0:(x,y) 1:(x,x) 2:(y,y)
    const float* xb = xg + (size_t)graph * (NPTS * DIM);
    const float* yb = yg + (size_t)graph * (NPTS * DIM);
    const float* Xp = (term == 2) ? yb : xb;
    const float* Yp = (term == 1) ? xb : yb;

    split_store(sxh, sxl, Xp, KLOG, tid);       // row side carries 1/eps scale
    split_store(syh, syl, Yp, 1.0f, tid);

    float csum;
    {
        const float hx = halfsq16(Xp + tid * DIM);
        const float hy = halfsq16(Yp + tid * DIM);
        csum = hx + hy;
        sG[NPTS + tid] = fmaf(-KLOG, hy, -10.0f);   // g_{-1} msgs -> gbuf[1]
        sF[NPTS + tid] = 0.0f;                      // finite placeholder
    }
    __syncthreads();

    u64 fmsk[RT], gmsk[RT];                      // wave-uniform tile masks
    float fsum = 0.0f, gsum = 0.0f;
    #pragma unroll 1
    for (int it = 0; it < NITERS; ++it) {
        const int cur = it & 1, alt = cur ^ 1;
        if (it < NWARM) {
            fsum = warm_pass(sxh, sxl, syh, syl, sG + alt * NPTS,
                             sF + alt * NPTS, sF + cur * NPTS,
                             sDfx + cur * 64, sDfn + cur * 64, fmsk, wbase, lane);
            gsum = warm_pass(syh, syl, sxh, sxl, sF + cur * NPTS,
                             sG + alt * NPTS, sG + cur * NPTS,
                             sDgx + cur * 64, sDgn + cur * 64, gmsk, wbase, lane);
        } else if (it == 8 || it == 14) {        // mask refresh checkpoints
            fsum = fused_pass<false, true>(sxh, sxl, syh, syl, sG + alt * NPTS,
                              sF + alt * NPTS, sF + cur * NPTS,
                              sDgx + alt * 64, sDgn + alt * 64,
                              sDfx + cur * 64, sDfn + cur * 64,
                              nullptr, fmsk, wbase, lane);
            gsum = fused_pass<false, true>(syh, syl, sxh, sxl, sF + cur * NPTS,
                              sG + alt * NPTS, sG + cur * NPTS,
                              sDfx + cur * 64, sDfn + cur * 64,
                              sDgx + cur * 64, sDgn + cur * 64,
                              nullptr, gmsk, wbase, lane);
        } else {                                  // masked fast passes
            fsum = fused_pass<true, false>(sxh, sxl, syh, syl, sG + alt * NPTS,
                              sF + alt * NPTS, sF + cur * NPTS,
                              sDgx + alt * 64, sDgn + alt * 64,
                              sDfx + cur * 64, sDfn + cur * 64,
                              fmsk, nullptr, wbase, lane);
            gsum = fused_pass<true, false>(syh, syl, sxh, sxl, sF + cur * NPTS,
                              sG + alt * NPTS, sG + cur * NPTS,
                              sDfx + cur * 64, sDfn + cur * 64,
                              sDgx + cur * 64, sDgn + cur * 64,
                              gmsk, nullptr, wbase, lane);
        }
    }
    // final f-pass i=20 (cur=0, alt=1), masked (mask from it=14, budgeted)
    fsum = fused_pass<true, false>(sxh, sxl, syh, syl, sG + 1 * NPTS,
                      sF + 1 * NPTS, sF + 0 * NPTS,
                      sDgx + 1 * 64, sDgn + 1 * 64,
                      sDfx + 0 * 64, sDfn + 0 * 64,
                      fmsk, nullptr, wbase, lane);

    // OT = [csum - CLSE*(sum lse_f + sum lse_g)] / NPTS  (lse sums x16 dup)
    float v = fmaf(-CLSE, (fsum + gsum) * (1.0f / 16.0f), csum);
    #pragma unroll
    for (int off = 32; off; off >>= 1) v += __shfl_down(v, off, 64);
    if (lane == 0) sF[NPTS + wave] = v;          // fbuf[1] is dead
    __syncthreads();
    if (tid == 0) {
        float tot = 0.0f;
        #pragma unroll
        for (int w = 0; w < NWAVES; ++w) tot += sF[NPTS + w];
        const float wgt = ((term == 0) ? 1.0f : -0.5f)
                          / ((float)GRAPHS * (float)NPTS);
        atomicAdd(out, wgt * tot);
    }
}

extern "C" void kernel_launch(void* const* d_in, const int* in_sizes, int n_in,
                              void* d_out, int out_size, void* d_ws, size_t ws_size,
                              hipStream_t stream)
{
    (void)in_sizes; (void)n_in; (void)d_ws; (void)ws_size; (void)out_size;
    const float* x = (const float*)d_in[0];
    const float* y = (const float*)d_in[1];
    float* out = (float*)d_out;

    constexpr size_t LDSB = 4 * NPTS * DIM * sizeof(__bf16)          // 128 KiB
                          + 4 * NPTS * sizeof(float)                 //  16 KiB
                          + 8 * 64 * sizeof(float);                  //   2 KiB
    hipFuncSetAttribute((const void*)sinkhorn_kernel,
                        hipFuncAttributeMaxDynamicSharedMemorySize, (int)LDSB);

    hipMemsetAsync(out, 0, sizeof(float), stream);
    hipLaunchKernelGGL(sinkhorn_kernel, dim3(GRAPHS * 3), dim3(THREADS), LDSB,
                       stream, x, y, out);
}

// Round 23
// 1026.383 us; speedup vs baseline: 1.3028x; 1.0292x over previous
//
#include <hip/hip_runtime.h>

#define NPTS    1024
#define DIM     16
#define GRAPHS  64
#define NITERS  20
#define THREADS 1024
#define NWAVES  (THREADS / 64)
#define RT      4        // 16-row tiles per wave (16 waves x 64 rows)
#define NCHUNK  16       // 64 j-tiles, 4 per chunk
#define WINW    80.0f    // prune window, warm two-phase passes
#define WINB    30.0f    // base prune window, fused full passes
#define WREC    90.0f    // mask-record window (prune 30 + 60 stale-drift budget)
#define NWARM   2        // exact two-phase iterations before fused passes
#define REFIT   11       // single mask-refresh iteration
#define MEOCAP  100.0f   // cap on baseline drift-overshoot (exp2 range guard)

typedef __bf16 bf16x8  __attribute__((ext_vector_type(8)));
typedef __bf16 bf16x4v __attribute__((ext_vector_type(4)));
typedef float  f32x4   __attribute__((ext_vector_type(4)));
typedef unsigned long long u64;

#define KLOG 577.07801635558536f      // log2(e)/eps, eps = 0.05^2
#define CLSE 0.0017328679513998633f   // eps*ln2   (KLOG*CLSE == 1)

static __device__ __forceinline__ float fexp2(float x){ return __builtin_amdgcn_exp2f(x); }
static __device__ __forceinline__ float flog2(float x){ return __builtin_amdgcn_logf(x); }

static __device__ __forceinline__ float halfsq16(const float* p)
{
    const float4* v = (const float4*)p;
    float a = 0.0f;
    #pragma unroll
    for (int c = 0; c < 4; ++c) {
        const float4 q = v[c];
        a = fmaf(q.x, q.x, a); a = fmaf(q.y, q.y, a);
        a = fmaf(q.z, q.z, a); a = fmaf(q.w, q.w, a);
    }
    return 0.5f * a;
}

// global f32 cloud -> LDS split-bf16 (hi, lo), optionally pre-scaled
static __device__ __forceinline__ void split_store(
    __bf16* __restrict__ dh, __bf16* __restrict__ dl,
    const float* __restrict__ src, const float scale, const int tid)
{
    const float4* s4 = (const float4*)src;
    #pragma unroll 1
    for (int k = 0; k < (NPTS * DIM / 4) / THREADS; ++k) {
        const int idx = tid + k * THREADS;
        const float4 v = s4[idx];
        const float f0 = v.x * scale, f1 = v.y * scale,
                    f2 = v.z * scale, f3 = v.w * scale;
        bf16x4v h, l;
        h[0] = (__bf16)f0; l[0] = (__bf16)(f0 - (float)h[0]);
        h[1] = (__bf16)f1; l[1] = (__bf16)(f1 - (float)h[1]);
        h[2] = (__bf16)f2; l[2] = (__bf16)(f2 - (float)h[2]);
        h[3] = (__bf16)f3; l[3] = (__bf16)(f3 - (float)h[3]);
        *(bf16x4v*)(dh + idx * 4) = h;
        *(bf16x4v*)(dl + idx * 4) = l;
    }
}

static __device__ __forceinline__ void loadA(
    bf16x8 A[RT], const __bf16* __restrict__ rH, const __bf16* __restrict__ rL,
    const int wbase, const int lane)
{
    const int g = lane >> 4, n = lane & 15, gh = g & 1;
    const __bf16* ap = (g < 2 ? rH : rL) + (wbase + n) * DIM + gh * 8;
    #pragma unroll
    for (int rt = 0; rt < RT; ++rt)
        A[rt] = *(const bf16x8*)(ap + rt * (16 * DIM));
}

// Full pruned exp-sum sweep over all 64 j-tiles, 3-deep MFMA rotation.
// Optionally RECORDs the active-tile bitmask (h > -WREC).
template<bool RECORD>
static __device__ __forceinline__ void sweep_sum_full(
    const bf16x8 A[RT], const __bf16* __restrict__ b1p,
    const __bf16* __restrict__ b2p, const float* __restrict__ tp,
    const float me[RT][4], const float win, float s[RT][4],
    u64* __restrict__ rec)
{
    if constexpr (RECORD) {
        #pragma unroll
        for (int r = 0; r < RT; ++r) rec[r] = 0ull;
    }
    #pragma unroll 1
    for (int c = 0; c < NCHUNK; ++c) {
        const int off = c * (4 * 16 * DIM);
        float t[4]; bf16x8 B1[4], B2[4];
        #pragma unroll
        for (int q = 0; q < 4; ++q) {
            t[q]  = tp[c * 64 + q * 16];
            B1[q] = *(const bf16x8*)(b1p + off + q * (16 * DIM));
            B2[q] = *(const bf16x8*)(b2p + off + q * (16 * DIM));
        }
        f32x4 w[3];
        #define ISSUE(kk, slot) do {                                          \
            const int q_ = (kk) >> 2, r_ = (kk) & 3;                          \
            f32x4 a_ = { t[q_] - me[r_][0], t[q_] - me[r_][1],                \
                         t[q_] - me[r_][2], t[q_] - me[r_][3] };              \
            a_ = __builtin_amdgcn_mfma_f32_16x16x32_bf16(A[r_], B2[q_], a_, 0, 0, 0); \
            w[slot] = __builtin_amdgcn_mfma_f32_16x16x32_bf16(A[r_], B1[q_], a_, 0, 0, 0); \
        } while (0)
        ISSUE(0, 0); ISSUE(1, 1);
        #pragma unroll
        for (int k = 0; k < 16; ++k) {
            if (k < 14) ISSUE(k + 2, (k + 2) % 3);
            const f32x4 wc = w[k % 3];
            const int rt = k & 3;
            const float h = fmaxf(fmaxf(wc[0], wc[1]), fmaxf(wc[2], wc[3]));
            if constexpr (RECORD) {
                if (__any(h > -WREC))
                    rec[rt] |= 1ull << (c * 4 + (k >> 2));
            }
            if (__any(h > -win)) {
                s[rt][0] += fexp2(wc[0]);
                s[rt][1] += fexp2(wc[1]);
                s[rt][2] += fexp2(wc[2]);
                s[rt][3] += fexp2(wc[3]);
            }
        }
        #undef ISSUE
    }
}

// Masked sweep: per row-tile (static rt), walk the set bits of its mask in
// pairs with 2-deep MFMA rotation (tile b1's MFMAs hide tile b0's latency).
// No per-tile prune re-check: recorded tiles always exp2 (sub-window terms
// underflow to 0 harmlessly). Mask bits are wave-uniform -> scalar branches.
static __device__ __forceinline__ void sweep_sum_masked(
    const bf16x8 A[RT], const __bf16* __restrict__ b1p,
    const __bf16* __restrict__ b2p, const float* __restrict__ tp,
    const float me[RT][4], float s[RT][4], const u64* __restrict__ msk)
{
    #pragma unroll
    for (int rt = 0; rt < RT; ++rt) {
        const float me0 = me[rt][0], me1 = me[rt][1],
                    me2 = me[rt][2], me3 = me[rt][3];
        float s0 = 0.0f, s1 = 0.0f, s2 = 0.0f, s3 = 0.0f;
        u64 bits = msk[rt];
        #pragma unroll 1
        while (bits) {
            const int b0 = (int)__builtin_ctzll(bits); bits &= bits - 1;
            const float t0 = tp[b0 * 16];
            f32x4 w0 = { t0 - me0, t0 - me1, t0 - me2, t0 - me3 };
            w0 = __builtin_amdgcn_mfma_f32_16x16x32_bf16(
                     A[rt], *(const bf16x8*)(b2p + b0 * 256), w0, 0, 0, 0);
            w0 = __builtin_amdgcn_mfma_f32_16x16x32_bf16(
                     A[rt], *(const bf16x8*)(b1p + b0 * 256), w0, 0, 0, 0);
            const bool has1 = (bits != 0ull);
            f32x4 w1;
            if (has1) {
                const int b1 = (int)__builtin_ctzll(bits); bits &= bits - 1;
                const float t1 = tp[b1 * 16];
                f32x4 a1 = { t1 - me0, t1 - me1, t1 - me2, t1 - me3 };
                a1 = __builtin_amdgcn_mfma_f32_16x16x32_bf16(
                         A[rt], *(const bf16x8*)(b2p + b1 * 256), a1, 0, 0, 0);
                w1 = __builtin_amdgcn_mfma_f32_16x16x32_bf16(
                         A[rt], *(const bf16x8*)(b1p + b1 * 256), a1, 0, 0, 0);
            }
            s0 += fexp2(w0[0]); s1 += fexp2(w0[1]);
            s2 += fexp2(w0[2]); s3 += fexp2(w0[3]);
            if (has1) {
                s0 += fexp2(w1[0]); s1 += fexp2(w1[1]);
                s2 += fexp2(w1[2]); s3 += fexp2(w1[3]);
            }
        }
        s[rt][0] += s0; s[rt][1] += s1; s[rt][2] += s2; s[rt][3] += s3;
    }
}

// Publish epilogue: n==0 lanes write fresh messages (bNew != any buffer read
// this pass) + drift partials vs bOld, then ONE barrier makes all visible.
static __device__ __forceinline__ void publish(
    const float lse[RT][4], const float* __restrict__ bOld,
    float* __restrict__ bNew, float* __restrict__ dOutX,
    float* __restrict__ dOutN, const int wbase, const int lane)
{
    const int g = lane >> 4, n = lane & 15;
    if (n == 0) {
        float dmx = -3.0e38f, dmn = 3.0e38f;
        #pragma unroll
        for (int rt = 0; rt < RT; ++rt) {
            const int row4 = wbase + rt * 16 + g * 4;
            const f32x4 old = *(const f32x4*)(bOld + row4);
            f32x4 mv;
            #pragma unroll
            for (int e = 0; e < 4; ++e) {
                mv[e] = -10.0f - lse[rt][e];
                const float d = mv[e] - old[e];
                dmx = fmaxf(dmx, d); dmn = fminf(dmn, d);
            }
            *(f32x4*)(bNew + row4) = mv;
        }
        dOutX[(wbase >> 4) + g] = dmx;
        dOutN[(wbase >> 4) + g] = dmn;
    }
    __syncthreads();
}

// Warm half-iteration: exact two-phase (max sweep + pruned sum); records mask.
static __device__ __forceinline__ float warm_pass(
    const __bf16* __restrict__ rH, const __bf16* __restrict__ rL,
    const __bf16* __restrict__ cH, const __bf16* __restrict__ cL,
    const float* __restrict__ tOld, const float* __restrict__ bOld,
    float* __restrict__ bNew, float* __restrict__ dOutX,
    float* __restrict__ dOutN, u64* __restrict__ rec,
    const int wbase, const int lane)
{
    const int g = lane >> 4, n = lane & 15, gh = g & 1;
    bf16x8 A[RT];
    loadA(A, rH, rL, wbase, lane);
    const __bf16* b1p = cH + n * DIM + gh * 8;
    const __bf16* b2p = cL + n * DIM + gh * 8;
    const float*  tp  = tOld + n;

    // pass 1: approx row maxima (B = hi only, 2-deep rotation)
    float m[RT][4];
    #pragma unroll
    for (int rt = 0; rt < RT; ++rt)
        #pragma unroll
        for (int e = 0; e < 4; ++e) m[rt][e] = -3.0e38f;

    #pragma unroll 1
    for (int c = 0; c < NCHUNK; ++c) {
        const int off = c * (4 * 16 * DIM);
        float t[4]; bf16x8 B[4];
        #pragma unroll
        for (int q = 0; q < 4; ++q) {
            t[q] = tp[c * 64 + q * 16];
            B[q] = *(const bf16x8*)(b1p + off + q * (16 * DIM));
        }
        f32x4 w[2];
        {
            f32x4 a0 = { t[0], t[0], t[0], t[0] };
            w[0] = __builtin_amdgcn_mfma_f32_16x16x32_bf16(A[0], B[0], a0, 0, 0, 0);
        }
        #pragma unroll
        for (int k = 0; k < 16; ++k) {
            if (k < 15) {
                const int kn = k + 1, qn = kn >> 2, rn = kn & 3;
                f32x4 a = { t[qn], t[qn], t[qn], t[qn] };
                w[kn & 1] = __builtin_amdgcn_mfma_f32_16x16x32_bf16(A[rn], B[qn], a, 0, 0, 0);
            }
            const f32x4 wc = w[k & 1];
            const int rt = k & 3;
            m[rt][0] = fmaxf(m[rt][0], wc[0]);
            m[rt][1] = fmaxf(m[rt][1], wc[1]);
            m[rt][2] = fmaxf(m[rt][2], wc[2]);
            m[rt][3] = fmaxf(m[rt][3], wc[3]);
        }
    }
    #pragma unroll
    for (int rt = 0; rt < RT; ++rt)
        #pragma unroll
        for (int e = 0; e < 4; ++e) {
            float mm = m[rt][e];
            #pragma unroll
            for (int d = 1; d < 16; d <<= 1)
                mm = fmaxf(mm, __shfl_xor(mm, d, 64));
            m[rt][e] = mm;
        }

    // pass 2: pruned exp-sums + mask record
    float s[RT][4];
    #pragma unroll
    for (int rt = 0; rt < RT; ++rt)
        #pragma unroll
        for (int e = 0; e < 4; ++e) s[rt][e] = 0.0f;
    sweep_sum_full<true>(A, b1p, b2p, tp, m, WINW, s, rec);

    float lsum = 0.0f;
    float lse[RT][4];
    #pragma unroll
    for (int rt = 0; rt < RT; ++rt)
        #pragma unroll
        for (int e = 0; e < 4; ++e) {
            float ss = s[rt][e];
            #pragma unroll
            for (int d = 1; d < 16; d <<= 1)
                ss += __shfl_xor(ss, d, 64);
            ss = fmaxf(ss, 1.0e-30f);
            const float l = m[rt][e] + flog2(ss);
            lsum += l;
            lse[rt][e] = l;
        }
    publish(lse, bOld, bNew, dOutX, dOutN, wbase, lane);
    return lsum;
}

// Fused half-iteration: single sweep; me = lse_prev + min(maxDrift, MEOCAP).
// LSE shift identity is exact for any me absent fp32 range issues; the cap
// bounds overshoot <= ~110 (< 126 underflow) and undershoot overflows only
// for drift > ~230 (not seen past iteration 1). MASKED walks recorded-
// active tiles only; RECORD refreshes the mask during a full sweep.
template<bool MASKED, bool RECORD>
static __device__ __forceinline__ float fused_pass(
    const __bf16* __restrict__ rH, const __bf16* __restrict__ rL,
    const __bf16* __restrict__ cH, const __bf16* __restrict__ cL,
    const float* __restrict__ tOld, const float* __restrict__ bOld,
    float* __restrict__ bNew,
    const float* __restrict__ dInX, const float* __restrict__ dInN,
    float* __restrict__ dOutX, float* __restrict__ dOutN,
    const u64* __restrict__ msk, u64* __restrict__ rec,
    const int wbase, const int lane)
{
    const int g = lane >> 4, n = lane & 15, gh = g & 1;
    bf16x8 A[RT];
    loadA(A, rH, rL, wbase, lane);

    // drift of the opposite-side messages from the preceding pass
    float dmx = dInX[lane], dmn = dInN[lane];
    #pragma unroll
    for (int d = 1; d < 64; d <<= 1) {
        dmx = fmaxf(dmx, __shfl_xor(dmx, d, 64));
        dmn = fminf(dmn, __shfl_xor(dmn, d, 64));
    }
    const float win  = WINB + fmaxf(0.0f, dmx - dmn);
    const float dmxc = fminf(dmx, MEOCAP);       // exp2-range guard

    float me[RT][4], s[RT][4];
    #pragma unroll
    for (int rt = 0; rt < RT; ++rt) {
        const f32x4 v = *(const f32x4*)(bOld + wbase + rt * 16 + g * 4);
        #pragma unroll
        for (int e = 0; e < 4; ++e) {
            me[rt][e] = (-10.0f - v[e]) + dmxc;  // lse_prev + drift bound
            s[rt][e]  = 0.0f;
        }
    }

    const __bf16* b1p = cH + n * DIM + gh * 8;
    const __bf16* b2p = cL + n * DIM + gh * 8;
    if constexpr (MASKED)
        sweep_sum_masked(A, b1p, b2p, tOld + n, me, s, msk);
    else
        sweep_sum_full<RECORD>(A, b1p, b2p, tOld + n, me, win, s, rec);

    float lsum = 0.0f;
    float lse[RT][4];
    #pragma unroll
    for (int rt = 0; rt < RT; ++rt)
        #pragma unroll
        for (int e = 0; e < 4; ++e) {
            float ss = (s[rt][e] > 1.0e-30f) ? s[rt][e] : 1.0e-30f;
            #pragma unroll
            for (int d = 1; d < 16; d <<= 1)
                ss += __shfl_xor(ss, d, 64);
            const float l = me[rt][e] + flog2(ss);
            lsum += l;
            lse[rt][e] = l;
        }
    publish(lse, bOld, bNew, dOutX, dOutN, wbase, lane);
    return lsum;
}

__global__ __launch_bounds__(THREADS)
void sinkhorn_kernel(const float* __restrict__ xg,
                     const float* __restrict__ yg,
                     float* __restrict__ out)
{
    extern __shared__ char ldsraw[];
    __bf16* sxh = (__bf16*)ldsraw;              // [1024][16] hi of K*x
    __bf16* sxl = sxh + NPTS * DIM;
    __bf16* syh = sxl + NPTS * DIM;
    __bf16* syl = syh + NPTS * DIM;
    float*  sF  = (float*)(syl + NPTS * DIM);   // [2][1024] f-messages
    float*  sG  = sF + 2 * NPTS;                // [2][1024] g-messages
    float*  sDfx = sG + 2 * NPTS;               // [2][64] f-drift max
    float*  sDfn = sDfx + 2 * 64;               // [2][64] f-drift min
    float*  sDgx = sDfn + 2 * 64;               // [2][64] g-drift max
    float*  sDgn = sDgx + 2 * 64;               // [2][64] g-drift min

    const int tid   = threadIdx.x;
    const int lane  = tid & 63;
    const int wave  = tid >> 6;
    const int wbase = wave * (RT * 16);

    const int graph = blockIdx.x / 3;
    const int term  = blockIdx.x - graph * 3;   // 0:(x,y) 1:(x,x) 2:(y,y)
    const float* xb = xg + (size_t)graph * (NPTS * DIM);
    const float* yb = yg + (size_t)graph * (NPTS * DIM);
    const float* Xp = (term == 2) ? yb : xb;
    const float* Yp = (term == 1) ? xb : yb;

    split_store(sxh, sxl, Xp, KLOG, tid);       // row side carries 1/eps scale
    split_store(syh, syl, Yp, 1.0f, tid);

    float csum;
    {
        const float hx = halfsq16(Xp + tid * DIM);
        const float hy = halfsq16(Yp + tid * DIM);
        csum = hx + hy;
        sG[NPTS + tid] = fmaf(-KLOG, hy, -10.0f);   // g_{-1} msgs -> gbuf[1]
        sF[NPTS + tid] = 0.0f;                      // finite placeholder
    }
    __syncthreads();

    u64 fmsk[RT], gmsk[RT];                      // wave-uniform tile masks
    float fsum = 0.0f, gsum = 0.0f;
    #pragma unroll 1
    for (int it = 0; it < NITERS; ++it) {
        const int cur = it & 1, alt = cur ^ 1;
        if (it < NWARM) {
            fsum = warm_pass(sxh, sxl, syh, syl, sG + alt * NPTS,
                             sF + alt * NPTS, sF + cur * NPTS,
                             sDfx + cur * 64, sDfn + cur * 64, fmsk, wbase, lane);
            gsum = warm_pass(syh, syl, sxh, sxl, sF + cur * NPTS,
                             sG + alt * NPTS, sG + cur * NPTS,
                             sDgx + cur * 64, sDgn + cur * 64, gmsk, wbase, lane);
        } else if (it == REFIT) {                // single mask refresh
            fsum = fused_pass<false, true>(sxh, sxl, syh, syl, sG + alt * NPTS,
                              sF + alt * NPTS, sF + cur * NPTS,
                              sDgx + alt * 64, sDgn + alt * 64,
                              sDfx + cur * 64, sDfn + cur * 64,
                              nullptr, fmsk, wbase, lane);
            gsum = fused_pass<false, true>(syh, syl, sxh, sxl, sF + cur * NPTS,
                              sG + alt * NPTS, sG + cur * NPTS,
                              sDfx + cur * 64, sDfn + cur * 64,
                              sDgx + cur * 64, sDgn + cur * 64,
                              nullptr, gmsk, wbase, lane);
        } else {                                  // masked fast passes
            fsum = fused_pass<true, false>(sxh, sxl, syh, syl, sG + alt * NPTS,
                              sF + alt * NPTS, sF + cur * NPTS,
                              sDgx + alt * 64, sDgn + alt * 64,
                              sDfx + cur * 64, sDfn + cur * 64,
                              fmsk, nullptr, wbase, lane);
            gsum = fused_pass<true, false>(syh, syl, sxh, sxl, sF + cur * NPTS,
                              sG + alt * NPTS, sG + cur * NPTS,
                              sDfx + cur * 64, sDfn + cur * 64,
                              sDgx + cur * 64, sDgn + cur * 64,
                              gmsk, nullptr, wbase, lane);
        }
    }
    // final f-pass i=20 (cur=0, alt=1), masked (mask from it=11, budgeted)
    fsum = fused_pass<true, false>(sxh, sxl, syh, syl, sG + 1 * NPTS,
                      sF + 1 * NPTS, sF + 0 * NPTS,
                      sDgx + 1 * 64, sDgn + 1 * 64,
                      sDfx + 0 * 64, sDfn + 0 * 64,
                      fmsk, nullptr, wbase, lane);

    // OT = [csum - CLSE*(sum lse_f + sum lse_g)] / NPTS  (lse sums x16 dup)
    float v = fmaf(-CLSE, (fsum + gsum) * (1.0f / 16.0f), csum);
    #pragma unroll
    for (int off = 32; off; off >>= 1) v += __shfl_down(v, off, 64);
    if (lane == 0) sF[NPTS + wave] = v;          // fbuf[1] is dead
    __syncthreads();
    if (tid == 0) {
        float tot = 0.0f;
        #pragma unroll
        for (int w = 0; w < NWAVES; ++w) tot += sF[NPTS + w];
        const float wgt = ((term == 0) ? 1.0f : -0.5f)
                          / ((float)GRAPHS * (float)NPTS);
        atomicAdd(out, wgt * tot);
    }
}

extern "C" void kernel_launch(void* const* d_in, const int* in_sizes, int n_in,
                              void* d_out, int out_size, void* d_ws, size_t ws_size,
                              hipStream_t stream)
{
    (void)in_sizes; (void)n_in; (void)d_ws; (void)ws_size; (void)out_size;
    const float* x = (const float*)d_in[0];
    const float* y = (const float*)d_in[1];
    float* out = (float*)d_out;

    constexpr size_t LDSB = 4 * NPTS * DIM * sizeof(__bf16)          // 128 KiB
                          + 4 * NPTS * sizeof(float)                 //  16 KiB
                          + 8 * 64 * sizeof(float);                  //   2 KiB
    hipFuncSetAttribute((const void*)sinkhorn_kernel,
                        hipFuncAttributeMaxDynamicSharedMemorySize, (int)LDSB);

    hipMemsetAsync(out, 0, sizeof(float), stream);
    hipLaunchKernelGGL(sinkhorn_kernel, dim3(GRAPHS * 3), dim3(THREADS), LDSB,
                       stream, x, y, out);
}

// Round 24
// 1020.114 us; speedup vs baseline: 1.3108x; 1.0061x over previous
//
#include <hip/hip_runtime.h>

#define NPTS    1024
#define DIM     16
#define GRAPHS  64
#define NITERS  20
#define THREADS 1024
#define NWAVES  (THREADS / 64)
#define RT      4        // 16-row tiles per wave (16 waves x 64 rows)
#define NCHUNK  16       // 64 j-tiles, 4 per chunk
#define WINW    80.0f    // prune window, warm two-phase passes
#define WINB    30.0f    // base prune window, fused full passes
#define WREC    90.0f    // mask-record window (prune 30 + 60 stale-drift budget)
#define NWARM   2        // exact two-phase iterations before fused passes
#define REFIT   11       // single mask-refresh iteration
#define MEOCAP  100.0f   // cap on baseline drift-overshoot (exp2 range guard)

typedef __bf16 bf16x8  __attribute__((ext_vector_type(8)));
typedef __bf16 bf16x4v __attribute__((ext_vector_type(4)));
typedef float  f32x4   __attribute__((ext_vector_type(4)));
typedef unsigned long long u64;

#define KLOG 577.07801635558536f      // log2(e)/eps, eps = 0.05^2
#define CLSE 0.0017328679513998633f   // eps*ln2   (KLOG*CLSE == 1)

static __device__ __forceinline__ float fexp2(float x){ return __builtin_amdgcn_exp2f(x); }
static __device__ __forceinline__ float flog2(float x){ return __builtin_amdgcn_logf(x); }

static __device__ __forceinline__ float halfsq16(const float* p)
{
    const float4* v = (const float4*)p;
    float a = 0.0f;
    #pragma unroll
    for (int c = 0; c < 4; ++c) {
        const float4 q = v[c];
        a = fmaf(q.x, q.x, a); a = fmaf(q.y, q.y, a);
        a = fmaf(q.z, q.z, a); a = fmaf(q.w, q.w, a);
    }
    return 0.5f * a;
}

// global f32 cloud -> LDS split-bf16 (hi, lo), optionally pre-scaled
static __device__ __forceinline__ void split_store(
    __bf16* __restrict__ dh, __bf16* __restrict__ dl,
    const float* __restrict__ src, const float scale, const int tid)
{
    const float4* s4 = (const float4*)src;
    #pragma unroll 1
    for (int k = 0; k < (NPTS * DIM / 4) / THREADS; ++k) {
        const int idx = tid + k * THREADS;
        const float4 v = s4[idx];
        const float f0 = v.x * scale, f1 = v.y * scale,
                    f2 = v.z * scale, f3 = v.w * scale;
        bf16x4v h, l;
        h[0] = (__bf16)f0; l[0] = (__bf16)(f0 - (float)h[0]);
        h[1] = (__bf16)f1; l[1] = (__bf16)(f1 - (float)h[1]);
        h[2] = (__bf16)f2; l[2] = (__bf16)(f2 - (float)h[2]);
        h[3] = (__bf16)f3; l[3] = (__bf16)(f3 - (float)h[3]);
        *(bf16x4v*)(dh + idx * 4) = h;
        *(bf16x4v*)(dl + idx * 4) = l;
    }
}

static __device__ __forceinline__ void loadA(
    bf16x8 A[RT], const __bf16* __restrict__ rH, const __bf16* __restrict__ rL,
    const int wbase, const int lane)
{
    const int g = lane >> 4, n = lane & 15, gh = g & 1;
    const __bf16* ap = (g < 2 ? rH : rL) + (wbase + n) * DIM + gh * 8;
    #pragma unroll
    for (int rt = 0; rt < RT; ++rt)
        A[rt] = *(const bf16x8*)(ap + rt * (16 * DIM));
}

// Full pruned exp-sum sweep over all 64 j-tiles, 3-deep MFMA rotation.
// Optionally RECORDs the active-tile bitmask (h > -WREC).
template<bool RECORD>
static __device__ __forceinline__ void sweep_sum_full(
    const bf16x8 A[RT], const __bf16* __restrict__ b1p,
    const __bf16* __restrict__ b2p, const float* __restrict__ tp,
    const float me[RT][4], const float win, float s[RT][4],
    u64* __restrict__ rec)
{
    if constexpr (RECORD) {
        #pragma unroll
        for (int r = 0; r < RT; ++r) rec[r] = 0ull;
    }
    #pragma unroll 1
    for (int c = 0; c < NCHUNK; ++c) {
        const int off = c * (4 * 16 * DIM);
        float t[4]; bf16x8 B1[4], B2[4];
        #pragma unroll
        for (int q = 0; q < 4; ++q) {
            t[q]  = tp[c * 64 + q * 16];
            B1[q] = *(const bf16x8*)(b1p + off + q * (16 * DIM));
            B2[q] = *(const bf16x8*)(b2p + off + q * (16 * DIM));
        }
        f32x4 w[3];
        #define ISSUE(kk, slot) do {                                          \
            const int q_ = (kk) >> 2, r_ = (kk) & 3;                          \
            f32x4 a_ = { t[q_] - me[r_][0], t[q_] - me[r_][1],                \
                         t[q_] - me[r_][2], t[q_] - me[r_][3] };              \
            a_ = __builtin_amdgcn_mfma_f32_16x16x32_bf16(A[r_], B2[q_], a_, 0, 0, 0); \
            w[slot] = __builtin_amdgcn_mfma_f32_16x16x32_bf16(A[r_], B1[q_], a_, 0, 0, 0); \
        } while (0)
        ISSUE(0, 0); ISSUE(1, 1);
        #pragma unroll
        for (int k = 0; k < 16; ++k) {
            if (k < 14) ISSUE(k + 2, (k + 2) % 3);
            const f32x4 wc = w[k % 3];
            const int rt = k & 3;
            const float h = fmaxf(fmaxf(wc[0], wc[1]), fmaxf(wc[2], wc[3]));
            if constexpr (RECORD) {
                if (__any(h > -WREC))
                    rec[rt] |= 1ull << (c * 4 + (k >> 2));
            }
            if (__any(h > -win)) {
                s[rt][0] += fexp2(wc[0]);
                s[rt][1] += fexp2(wc[1]);
                s[rt][2] += fexp2(wc[2]);
                s[rt][3] += fexp2(wc[3]);
            }
        }
        #undef ISSUE
    }
}

// Masked sweep: per row-tile (static rt), walk the set bits of its mask FOUR
// tiles per loop iteration (wave-uniform guards). The wide iteration exposes
// 4 independent {t/B loads -> MFMA pair -> exp2} chains to the scheduler so
// LDS latency of later tiles hides under earlier tiles' math. Accumulation
// stays in bit order per rt (numerically identical to the pair version).
static __device__ __forceinline__ void sweep_sum_masked(
    const bf16x8 A[RT], const __bf16* __restrict__ b1p,
    const __bf16* __restrict__ b2p, const float* __restrict__ tp,
    const float me[RT][4], float s[RT][4], const u64* __restrict__ msk)
{
    #pragma unroll
    for (int rt = 0; rt < RT; ++rt) {
        const float me0 = me[rt][0], me1 = me[rt][1],
                    me2 = me[rt][2], me3 = me[rt][3];
        float s0 = 0.0f, s1 = 0.0f, s2 = 0.0f, s3 = 0.0f;
        u64 bits = msk[rt];

        #define TILE_MFMA(bi, wdst) do {                                      \
            const float t_ = tp[(bi) * 16];                                   \
            f32x4 a_ = { t_ - me0, t_ - me1, t_ - me2, t_ - me3 };            \
            a_ = __builtin_amdgcn_mfma_f32_16x16x32_bf16(                     \
                     A[rt], *(const bf16x8*)(b2p + (bi) * 256), a_, 0, 0, 0); \
            wdst = __builtin_amdgcn_mfma_f32_16x16x32_bf16(                   \
                     A[rt], *(const bf16x8*)(b1p + (bi) * 256), a_, 0, 0, 0); \
        } while (0)
        #define TILE_SUM(wv) do {                                             \
            s0 += fexp2((wv)[0]); s1 += fexp2((wv)[1]);                       \
            s2 += fexp2((wv)[2]); s3 += fexp2((wv)[3]);                       \
        } while (0)

        #pragma unroll 1
        while (bits) {
            const int b0 = (int)__builtin_ctzll(bits); bits &= bits - 1;
            f32x4 w0; TILE_MFMA(b0, w0);
            const bool has1 = (bits != 0ull);
            f32x4 w1;
            int b1 = 0;
            if (has1) { b1 = (int)__builtin_ctzll(bits); bits &= bits - 1;
                        TILE_MFMA(b1, w1); }
            const bool has2 = (bits != 0ull);
            f32x4 w2;
            int b2 = 0;
            if (has2) { b2 = (int)__builtin_ctzll(bits); bits &= bits - 1;
                        TILE_MFMA(b2, w2); }
            const bool has3 = (bits != 0ull);
            f32x4 w3;
            int b3 = 0;
            if (has3) { b3 = (int)__builtin_ctzll(bits); bits &= bits - 1;
                        TILE_MFMA(b3, w3); }
            TILE_SUM(w0);
            if (has1) TILE_SUM(w1);
            if (has2) TILE_SUM(w2);
            if (has3) TILE_SUM(w3);
        }
        #undef TILE_MFMA
        #undef TILE_SUM
        s[rt][0] += s0; s[rt][1] += s1; s[rt][2] += s2; s[rt][3] += s3;
    }
}

// Publish epilogue: n==0 lanes write fresh messages (bNew != any buffer read
// this pass) + drift partials vs bOld, then ONE barrier makes all visible.
static __device__ __forceinline__ void publish(
    const float lse[RT][4], const float* __restrict__ bOld,
    float* __restrict__ bNew, float* __restrict__ dOutX,
    float* __restrict__ dOutN, const int wbase, const int lane)
{
    const int g = lane >> 4, n = lane & 15;
    if (n == 0) {
        float dmx = -3.0e38f, dmn = 3.0e38f;
        #pragma unroll
        for (int rt = 0; rt < RT; ++rt) {
            const int row4 = wbase + rt * 16 + g * 4;
            const f32x4 old = *(const f32x4*)(bOld + row4);
            f32x4 mv;
            #pragma unroll
            for (int e = 0; e < 4; ++e) {
                mv[e] = -10.0f - lse[rt][e];
                const float d = mv[e] - old[e];
                dmx = fmaxf(dmx, d); dmn = fminf(dmn, d);
            }
            *(f32x4*)(bNew + row4) = mv;
        }
        dOutX[(wbase >> 4) + g] = dmx;
        dOutN[(wbase >> 4) + g] = dmn;
    }
    __syncthreads();
}

// Warm half-iteration: exact two-phase (max sweep + pruned sum); records mask.
static __device__ __forceinline__ float warm_pass(
    const __bf16* __restrict__ rH, const __bf16* __restrict__ rL,
    const __bf16* __restrict__ cH, const __bf16* __restrict__ cL,
    const float* __restrict__ tOld, const float* __restrict__ bOld,
    float* __restrict__ bNew, float* __restrict__ dOutX,
    float* __restrict__ dOutN, u64* __restrict__ rec,
    const int wbase, const int lane)
{
    const int g = lane >> 4, n = lane & 15, gh = g & 1;
    bf16x8 A[RT];
    loadA(A, rH, rL, wbase, lane);
    const __bf16* b1p = cH + n * DIM + gh * 8;
    const __bf16* b2p = cL + n * DIM + gh * 8;
    const float*  tp  = tOld + n;

    // pass 1: approx row maxima (B = hi only, 2-deep rotation)
    float m[RT][4];
    #pragma unroll
    for (int rt = 0; rt < RT; ++rt)
        #pragma unroll
        for (int e = 0; e < 4; ++e) m[rt][e] = -3.0e38f;

    #pragma unroll 1
    for (int c = 0; c < NCHUNK; ++c) {
        const int off = c * (4 * 16 * DIM);
        float t[4]; bf16x8 B[4];
        #pragma unroll
        for (int q = 0; q < 4; ++q) {
            t[q] = tp[c * 64 + q * 16];
            B[q] = *(const bf16x8*)(b1p + off + q * (16 * DIM));
        }
        f32x4 w[2];
        {
            f32x4 a0 = { t[0], t[0], t[0], t[0] };
            w[0] = __builtin_amdgcn_mfma_f32_16x16x32_bf16(A[0], B[0], a0, 0, 0, 0);
        }
        #pragma unroll
        for (int k = 0; k < 16; ++k) {
            if (k < 15) {
                const int kn = k + 1, qn = kn >> 2, rn = kn & 3;
                f32x4 a = { t[qn], t[qn], t[qn], t[qn] };
                w[kn & 1] = __builtin_amdgcn_mfma_f32_16x16x32_bf16(A[rn], B[qn], a, 0, 0, 0);
            }
            const f32x4 wc = w[k & 1];
            const int rt = k & 3;
            m[rt][0] = fmaxf(m[rt][0], wc[0]);
            m[rt][1] = fmaxf(m[rt][1], wc[1]);
            m[rt][2] = fmaxf(m[rt][2], wc[2]);
            m[rt][3] = fmaxf(m[rt][3], wc[3]);
        }
    }
    #pragma unroll
    for (int rt = 0; rt < RT; ++rt)
        #pragma unroll
        for (int e = 0; e < 4; ++e) {
            float mm = m[rt][e];
            #pragma unroll
            for (int d = 1; d < 16; d <<= 1)
                mm = fmaxf(mm, __shfl_xor(mm, d, 64));
            m[rt][e] = mm;
        }

    // pass 2: pruned exp-sums + mask record
    float s[RT][4];
    #pragma unroll
    for (int rt = 0; rt < RT; ++rt)
        #pragma unroll
        for (int e = 0; e < 4; ++e) s[rt][e] = 0.0f;
    sweep_sum_full<true>(A, b1p, b2p, tp, m, WINW, s, rec);

    float lsum = 0.0f;
    float lse[RT][4];
    #pragma unroll
    for (int rt = 0; rt < RT; ++rt)
        #pragma unroll
        for (int e = 0; e < 4; ++e) {
            float ss = s[rt][e];
            #pragma unroll
            for (int d = 1; d < 16; d <<= 1)
                ss += __shfl_xor(ss, d, 64);
            ss = fmaxf(ss, 1.0e-30f);
            const float l = m[rt][e] + flog2(ss);
            lsum += l;
            lse[rt][e] = l;
        }
    publish(lse, bOld, bNew, dOutX, dOutN, wbase, lane);
    return lsum;
}

// Fused half-iteration: single sweep; me = lse_prev + min(maxDrift, MEOCAP).
// LSE shift identity is exact for any me absent fp32 range issues; the cap
// bounds overshoot <= ~110 (< 126 underflow) and undershoot overflows only
// for drift > ~230 (not seen past iteration 1). MASKED walks recorded-
// active tiles only; RECORD refreshes the mask during a full sweep.
template<bool MASKED, bool RECORD>
static __device__ __forceinline__ float fused_pass(
    const __bf16* __restrict__ rH, const __bf16* __restrict__ rL,
    const __bf16* __restrict__ cH, const __bf16* __restrict__ cL,
    const float* __restrict__ tOld, const float* __restrict__ bOld,
    float* __restrict__ bNew,
    const float* __restrict__ dInX, const float* __restrict__ dInN,
    float* __restrict__ dOutX, float* __restrict__ dOutN,
    const u64* __restrict__ msk, u64* __restrict__ rec,
    const int wbase, const int lane)
{
    const int g = lane >> 4, n = lane & 15, gh = g & 1;
    bf16x8 A[RT];
    loadA(A, rH, rL, wbase, lane);

    // drift of the opposite-side messages from the preceding pass
    float dmx = dInX[lane], dmn = dInN[lane];
    #pragma unroll
    for (int d = 1; d < 64; d <<= 1) {
        dmx = fmaxf(dmx, __shfl_xor(dmx, d, 64));
        dmn = fminf(dmn, __shfl_xor(dmn, d, 64));
    }
    const float win  = WINB + fmaxf(0.0f, dmx - dmn);
    const float dmxc = fminf(dmx, MEOCAP);       // exp2-range guard

    float me[RT][4], s[RT][4];
    #pragma unroll
    for (int rt = 0; rt < RT; ++rt) {
        const f32x4 v = *(const f32x4*)(bOld + wbase + rt * 16 + g * 4);
        #pragma unroll
        for (int e = 0; e < 4; ++e) {
            me[rt][e] = (-10.0f - v[e]) + dmxc;  // lse_prev + drift bound
            s[rt][e]  = 0.0f;
        }
    }

    const __bf16* b1p = cH + n * DIM + gh * 8;
    const __bf16* b2p = cL + n * DIM + gh * 8;
    if constexpr (MASKED)
        sweep_sum_masked(A, b1p, b2p, tOld + n, me, s, msk);
    else
        sweep_sum_full<RECORD>(A, b1p, b2p, tOld + n, me, win, s, rec);

    float lsum = 0.0f;
    float lse[RT][4];
    #pragma unroll
    for (int rt = 0; rt < RT; ++rt)
        #pragma unroll
        for (int e = 0; e < 4; ++e) {
            float ss = (s[rt][e] > 1.0e-30f) ? s[rt][e] : 1.0e-30f;
            #pragma unroll
            for (int d = 1; d < 16; d <<= 1)
                ss += __shfl_xor(ss, d, 64);
            const float l = me[rt][e] + flog2(ss);
            lsum += l;
            lse[rt][e] = l;
        }
    publish(lse, bOld, bNew, dOutX, dOutN, wbase, lane);
    return lsum;
}

__global__ __launch_bounds__(THREADS)
void sinkhorn_kernel(const float* __restrict__ xg,
                     const float* __restrict__ yg,
                     float* __restrict__ out)
{
    extern __shared__ char ldsraw[];
    __bf16* sxh = (__bf16*)ldsraw;              // [1024][16] hi of K*x
    __bf16* sxl = sxh + NPTS * DIM;
    __bf16* syh = sxl + NPTS * DIM;
    __bf16* syl = syh + NPTS * DIM;
    float*  sF  = (float*)(syl + NPTS * DIM);   // [2][1024] f-messages
    float*  sG  = sF + 2 * NPTS;                // [2][1024] g-messages
    float*  sDfx = sG + 2 * NPTS;               // [2][64] f-drift max
    float*  sDfn = sDfx + 2 * 64;               // [2][64] f-drift min
    float*  sDgx = sDfn + 2 * 64;               // [2][64] g-drift max
    float*  sDgn = sDgx + 2 * 64;               // [2][64] g-drift min

    const int tid   = threadIdx.x;
    const int lane  = tid & 63;
    const int wave  = tid >> 6;
    const int wbase = wave * (RT * 16);

    const int graph = blockIdx.x / 3;
    const int term  = blockIdx.x - graph * 3;   // 0:(x,y) 1:(x,x) 2:(y,y)
    const float* xb = xg + (size_t)graph * (NPTS * DIM);
    const float* yb = yg + (size_t)graph * (NPTS * DIM);
    const float* Xp = (term == 2) ? yb : xb;
    const float* Yp = (term == 1) ? xb : yb;

    split_store(sxh, sxl, Xp, KLOG, tid);       // row side carries 1/eps scale
    split_store(syh, syl, Yp, 1.0f, tid);

    float csum;
    {
        const float hx = halfsq16(Xp + tid * DIM);
        const float hy = halfsq16(Yp + tid * DIM);
        csum = hx + hy;
        sG[NPTS + tid] = fmaf(-KLOG, hy, -10.0f);   // g_{-1} msgs -> gbuf[1]
        sF[NPTS + tid] = 0.0f;                      // finite placeholder
    }
    __syncthreads();

    u64 fmsk[RT], gmsk[RT];                      // wave-uniform tile masks
    float fsum = 0.0f, gsum = 0.0f;
    #pragma unroll 1
    for (int it = 0; it < NITERS; ++it) {
        const int cur = it & 1, alt = cur ^ 1;
        if (it < NWARM) {
            fsum = warm_pass(sxh, sxl, syh, syl, sG + alt * NPTS,
                             sF + alt * NPTS, sF + cur * NPTS,
                             sDfx + cur * 64, sDfn + cur * 64, fmsk, wbase, lane);
            gsum = warm_pass(syh, syl, sxh, sxl, sF + cur * NPTS,
                             sG + alt * NPTS, sG + cur * NPTS,
                             sDgx + cur * 64, sDgn + cur * 64, gmsk, wbase, lane);
        } else if (it == REFIT) {                // single mask refresh
            fsum = fused_pass<false, true>(sxh, sxl, syh, syl, sG + alt * NPTS,
                              sF + alt * NPTS, sF + cur * NPTS,
                              sDgx + alt * 64, sDgn + alt * 64,
                              sDfx + cur * 64, sDfn + cur * 64,
                              nullptr, fmsk, wbase, lane);
            gsum = fused_pass<false, true>(syh, syl, sxh, sxl, sF + cur * NPTS,
                              sG + alt * NPTS, sG + cur * NPTS,
                              sDfx + cur * 64, sDfn + cur * 64,
                              sDgx + cur * 64, sDgn + cur * 64,
                              nullptr, gmsk, wbase, lane);
        } else {                                  // masked fast passes
            fsum = fused_pass<true, false>(sxh, sxl, syh, syl, sG + alt * NPTS,
                              sF + alt * NPTS, sF + cur * NPTS,
                              sDgx + alt * 64, sDgn + alt * 64,
                              sDfx + cur * 64, sDfn + cur * 64,
                              fmsk, nullptr, wbase, lane);
            gsum = fused_pass<true, false>(syh, syl, sxh, sxl, sF + cur * NPTS,
                              sG + alt * NPTS, sG + cur * NPTS,
                              sDfx + cur * 64, sDfn + cur * 64,
                              sDgx + cur * 64, sDgn + cur * 64,
                              gmsk, nullptr, wbase, lane);
        }
    }
    // final f-pass i=20 (cur=0, alt=1), masked (mask from it=11, budgeted)
    fsum = fused_pass<true, false>(sxh, sxl, syh, syl, sG + 1 * NPTS,
                      sF + 1 * NPTS, sF + 0 * NPTS,
                      sDgx + 1 * 64, sDgn + 1 * 64,
                      sDfx + 0 * 64, sDfn + 0 * 64,
                      fmsk, nullptr, wbase, lane);

    // OT = [csum - CLSE*(sum lse_f + sum lse_g)] / NPTS  (lse sums x16 dup)
    float v = fmaf(-CLSE, (fsum + gsum) * (1.0f / 16.0f), csum);
    #pragma unroll
    for (int off = 32; off; off >>= 1) v += __shfl_down(v, off, 64);
    if (lane == 0) sF[NPTS + wave] = v;          // fbuf[1] is dead
    __syncthreads();
    if (tid == 0) {
        float tot = 0.0f;
        #pragma unroll
        for (int w = 0; w < NWAVES; ++w) tot += sF[NPTS + w];
        const float wgt = ((term == 0) ? 1.0f : -0.5f)
                          / ((float)GRAPHS * (float)NPTS);
        atomicAdd(out, wgt * tot);
    }
}

extern "C" void kernel_launch(void* const* d_in, const int* in_sizes, int n_in,
                              void* d_out, int out_size, void* d_ws, size_t ws_size,
                              hipStream_t stream)
{
    (void)in_sizes; (void)n_in; (void)d_ws; (void)ws_size; (void)out_size;
    const float* x = (const float*)d_in[0];
    const float* y = (const float*)d_in[1];
    float* out = (float*)d_out;

    constexpr size_t LDSB = 4 * NPTS * DIM * sizeof(__bf16)          // 128 KiB
                          + 4 * NPTS * sizeof(float)                 //  16 KiB
                          + 8 * 64 * sizeof(float);                  //   2 KiB
    hipFuncSetAttribute((const void*)sinkhorn_kernel,
                        hipFuncAttributeMaxDynamicSharedMemorySize, (int)LDSB);

    hipMemsetAsync(out, 0, sizeof(float), stream);
    hipLaunchKernelGGL(sinkhorn_kernel, dim3(GRAPHS * 3), dim3(THREADS), LDSB,
                       stream, x, y, out);
}

// Round 25
// 1019.655 us; speedup vs baseline: 1.3114x; 1.0004x over previous
//
#include <hip/hip_runtime.h>

#define NPTS    1024
#define DIM     16
#define GRAPHS  64
#define NITERS  20
#define THREADS 1024
#define NWAVES  (THREADS / 64)
#define RT      4        // 16-row tiles per wave (16 waves x 64 rows)
#define NCHUNK  16       // 64 j-tiles, 4 per chunk
#define WINW    80.0f    // prune window, warm two-phase passes
#define WINB    30.0f    // base prune window, fused full passes
#define WREC    90.0f    // mask-record window (prune 30 + 60 stale-drift budget)
#define NWARM   2        // exact two-phase iterations before fused passes
#define REFIT   11       // single mask-refresh iteration
#define MEOCAP  100.0f   // cap on baseline drift-overshoot (exp2 range guard)

typedef __bf16 bf16x8  __attribute__((ext_vector_type(8)));
typedef __bf16 bf16x4v __attribute__((ext_vector_type(4)));
typedef float  f32x4   __attribute__((ext_vector_type(4)));
typedef unsigned long long u64;

#define KLOG 577.07801635558536f      // log2(e)/eps, eps = 0.05^2
#define CLSE 0.0017328679513998633f   // eps*ln2   (KLOG*CLSE == 1)

static __device__ __forceinline__ float fexp2(float x){ return __builtin_amdgcn_exp2f(x); }
static __device__ __forceinline__ float flog2(float x){ return __builtin_amdgcn_logf(x); }

static __device__ __forceinline__ float halfsq16(const float* p)
{
    const float4* v = (const float4*)p;
    float a = 0.0f;
    #pragma unroll
    for (int c = 0; c < 4; ++c) {
        const float4 q = v[c];
        a = fmaf(q.x, q.x, a); a = fmaf(q.y, q.y, a);
        a = fmaf(q.z, q.z, a); a = fmaf(q.w, q.w, a);
    }
    return 0.5f * a;
}

// global f32 cloud -> LDS split-bf16 (hi, lo), optionally pre-scaled
static __device__ __forceinline__ void split_store(
    __bf16* __restrict__ dh, __bf16* __restrict__ dl,
    const float* __restrict__ src, const float scale, const int tid)
{
    const float4* s4 = (const float4*)src;
    #pragma unroll 1
    for (int k = 0; k < (NPTS * DIM / 4) / THREADS; ++k) {
        const int idx = tid + k * THREADS;
        const float4 v = s4[idx];
        const float f0 = v.x * scale, f1 = v.y * scale,
                    f2 = v.z * scale, f3 = v.w * scale;
        bf16x4v h, l;
        h[0] = (__bf16)f0; l[0] = (__bf16)(f0 - (float)h[0]);
        h[1] = (__bf16)f1; l[1] = (__bf16)(f1 - (float)h[1]);
        h[2] = (__bf16)f2; l[2] = (__bf16)(f2 - (float)h[2]);
        h[3] = (__bf16)f3; l[3] = (__bf16)(f3 - (float)h[3]);
        *(bf16x4v*)(dh + idx * 4) = h;
        *(bf16x4v*)(dl + idx * 4) = l;
    }
}

static __device__ __forceinline__ void loadA(
    bf16x8 A[RT], const __bf16* __restrict__ rH, const __bf16* __restrict__ rL,
    const int wbase, const int lane)
{
    const int g = lane >> 4, n = lane & 15, gh = g & 1;
    const __bf16* ap = (g < 2 ? rH : rL) + (wbase + n) * DIM + gh * 8;
    #pragma unroll
    for (int rt = 0; rt < RT; ++rt)
        A[rt] = *(const bf16x8*)(ap + rt * (16 * DIM));
}

// Full pruned exp-sum sweep over all 64 j-tiles, 3-deep MFMA rotation.
// Optionally RECORDs the active-tile bitmask (h > -WREC).
template<bool RECORD>
static __device__ __forceinline__ void sweep_sum_full(
    const bf16x8 A[RT], const __bf16* __restrict__ b1p,
    const __bf16* __restrict__ b2p, const float* __restrict__ tp,
    const float me[RT][4], const float win, float s[RT][4],
    u64* __restrict__ rec)
{
    if constexpr (RECORD) {
        #pragma unroll
        for (int r = 0; r < RT; ++r) rec[r] = 0ull;
    }
    #pragma unroll 1
    for (int c = 0; c < NCHUNK; ++c) {
        const int off = c * (4 * 16 * DIM);
        float t[4]; bf16x8 B1[4], B2[4];
        #pragma unroll
        for (int q = 0; q < 4; ++q) {
            t[q]  = tp[c * 64 + q * 16];
            B1[q] = *(const bf16x8*)(b1p + off + q * (16 * DIM));
            B2[q] = *(const bf16x8*)(b2p + off + q * (16 * DIM));
        }
        f32x4 w[3];
        #define ISSUE(kk, slot) do {                                          \
            const int q_ = (kk) >> 2, r_ = (kk) & 3;                          \
            f32x4 a_ = { t[q_] - me[r_][0], t[q_] - me[r_][1],                \
                         t[q_] - me[r_][2], t[q_] - me[r_][3] };              \
            a_ = __builtin_amdgcn_mfma_f32_16x16x32_bf16(A[r_], B2[q_], a_, 0, 0, 0); \
            w[slot] = __builtin_amdgcn_mfma_f32_16x16x32_bf16(A[r_], B1[q_], a_, 0, 0, 0); \
        } while (0)
        ISSUE(0, 0); ISSUE(1, 1);
        #pragma unroll
        for (int k = 0; k < 16; ++k) {
            if (k < 14) ISSUE(k + 2, (k + 2) % 3);
            const f32x4 wc = w[k % 3];
            const int rt = k & 3;
            const float h = fmaxf(fmaxf(wc[0], wc[1]), fmaxf(wc[2], wc[3]));
            if constexpr (RECORD) {
                if (__any(h > -WREC))
                    rec[rt] |= 1ull << (c * 4 + (k >> 2));
            }
            if (__any(h > -win)) {
                s[rt][0] += fexp2(wc[0]);
                s[rt][1] += fexp2(wc[1]);
                s[rt][2] += fexp2(wc[2]);
                s[rt][3] += fexp2(wc[3]);
            }
        }
        #undef ISSUE
    }
}

// Masked sweep: per row-tile (static rt), walk the set bits of its mask FOUR
// tiles per loop iteration (wave-uniform guards). The wide iteration exposes
// 4 independent {t/B loads -> MFMA pair -> exp2} chains to the scheduler so
// LDS latency of later tiles hides under earlier tiles' math. Accumulation
// stays in bit order per rt (numerically identical to the pair version).
static __device__ __forceinline__ void sweep_sum_masked(
    const bf16x8 A[RT], const __bf16* __restrict__ b1p,
    const __bf16* __restrict__ b2p, const float* __restrict__ tp,
    const float me[RT][4], float s[RT][4], const u64* __restrict__ msk)
{
    #pragma unroll
    for (int rt = 0; rt < RT; ++rt) {
        const float me0 = me[rt][0], me1 = me[rt][1],
                    me2 = me[rt][2], me3 = me[rt][3];
        float s0 = 0.0f, s1 = 0.0f, s2 = 0.0f, s3 = 0.0f;
        u64 bits = msk[rt];

        #define TILE_MFMA(bi, wdst) do {                                      \
            const float t_ = tp[(bi) * 16];                                   \
            f32x4 a_ = { t_ - me0, t_ - me1, t_ - me2, t_ - me3 };            \
            a_ = __builtin_amdgcn_mfma_f32_16x16x32_bf16(                     \
                     A[rt], *(const bf16x8*)(b2p + (bi) * 256), a_, 0, 0, 0); \
            wdst = __builtin_amdgcn_mfma_f32_16x16x32_bf16(                   \
                     A[rt], *(const bf16x8*)(b1p + (bi) * 256), a_, 0, 0, 0); \
        } while (0)
        #define TILE_SUM(wv) do {                                             \
            s0 += fexp2((wv)[0]); s1 += fexp2((wv)[1]);                       \
            s2 += fexp2((wv)[2]); s3 += fexp2((wv)[3]);                       \
        } while (0)

        #pragma unroll 1
        while (bits) {
            const int b0 = (int)__builtin_ctzll(bits); bits &= bits - 1;
            f32x4 w0; TILE_MFMA(b0, w0);
            const bool has1 = (bits != 0ull);
            f32x4 w1;
            int b1 = 0;
            if (has1) { b1 = (int)__builtin_ctzll(bits); bits &= bits - 1;
                        TILE_MFMA(b1, w1); }
            const bool has2 = (bits != 0ull);
            f32x4 w2;
            int b2 = 0;
            if (has2) { b2 = (int)__builtin_ctzll(bits); bits &= bits - 1;
                        TILE_MFMA(b2, w2); }
            const bool has3 = (bits != 0ull);
            f32x4 w3;
            int b3 = 0;
            if (has3) { b3 = (int)__builtin_ctzll(bits); bits &= bits - 1;
                        TILE_MFMA(b3, w3); }
            TILE_SUM(w0);
            if (has1) TILE_SUM(w1);
            if (has2) TILE_SUM(w2);
            if (has3) TILE_SUM(w3);
        }
        #undef TILE_MFMA
        #undef TILE_SUM
        s[rt][0] += s0; s[rt][1] += s1; s[rt][2] += s2; s[rt][3] += s3;
    }
}

// Publish epilogue: n==0 lanes write fresh messages (bNew != any buffer read
// this pass) + drift partials vs bOld, then ONE barrier makes all visible.
static __device__ __forceinline__ void publish(
    const float lse[RT][4], const float* __restrict__ bOld,
    float* __restrict__ bNew, float* __restrict__ dOutX,
    float* __restrict__ dOutN, const int wbase, const int lane)
{
    const int g = lane >> 4, n = lane & 15;
    if (n == 0) {
        float dmx = -3.0e38f, dmn = 3.0e38f;
        #pragma unroll
        for (int rt = 0; rt < RT; ++rt) {
            const int row4 = wbase + rt * 16 + g * 4;
            const f32x4 old = *(const f32x4*)(bOld + row4);
            f32x4 mv;
            #pragma unroll
            for (int e = 0; e < 4; ++e) {
                mv[e] = -10.0f - lse[rt][e];
                const float d = mv[e] - old[e];
                dmx = fmaxf(dmx, d); dmn = fminf(dmn, d);
            }
            *(f32x4*)(bNew + row4) = mv;
        }
        dOutX[(wbase >> 4) + g] = dmx;
        dOutN[(wbase >> 4) + g] = dmn;
    }
    __syncthreads();
}

// Warm half-iteration: exact two-phase (max sweep + pruned sum); records mask.
static __device__ __forceinline__ float warm_pass(
    const __bf16* __restrict__ rH, const __bf16* __restrict__ rL,
    const __bf16* __restrict__ cH, const __bf16* __restrict__ cL,
    const float* __restrict__ tOld, const float* __restrict__ bOld,
    float* __restrict__ bNew, float* __restrict__ dOutX,
    float* __restrict__ dOutN, u64* __restrict__ rec,
    const int wbase, const int lane)
{
    const int g = lane >> 4, n = lane & 15, gh = g & 1;
    bf16x8 A[RT];
    loadA(A, rH, rL, wbase, lane);
    const __bf16* b1p = cH + n * DIM + gh * 8;
    const __bf16* b2p = cL + n * DIM + gh * 8;
    const float*  tp  = tOld + n;

    // pass 1: approx row maxima (B = hi only, 2-deep rotation)
    float m[RT][4];
    #pragma unroll
    for (int rt = 0; rt < RT; ++rt)
        #pragma unroll
        for (int e = 0; e < 4; ++e) m[rt][e] = -3.0e38f;

    #pragma unroll 1
    for (int c = 0; c < NCHUNK; ++c) {
        const int off = c * (4 * 16 * DIM);
        float t[4]; bf16x8 B[4];
        #pragma unroll
        for (int q = 0; q < 4; ++q) {
            t[q] = tp[c * 64 + q * 16];
            B[q] = *(const bf16x8*)(b1p + off + q * (16 * DIM));
        }
        f32x4 w[2];
        {
            f32x4 a0 = { t[0], t[0], t[0], t[0] };
            w[0] = __builtin_amdgcn_mfma_f32_16x16x32_bf16(A[0], B[0], a0, 0, 0, 0);
        }
        #pragma unroll
        for (int k = 0; k < 16; ++k) {
            if (k < 15) {
                const int kn = k + 1, qn = kn >> 2, rn = kn & 3;
                f32x4 a = { t[qn], t[qn], t[qn], t[qn] };
                w[kn & 1] = __builtin_amdgcn_mfma_f32_16x16x32_bf16(A[rn], B[qn], a, 0, 0, 0);
            }
            const f32x4 wc = w[k & 1];
            const int rt = k & 3;
            m[rt][0] = fmaxf(m[rt][0], wc[0]);
            m[rt][1] = fmaxf(m[rt][1], wc[1]);
            m[rt][2] = fmaxf(m[rt][2], wc[2]);
            m[rt][3] = fmaxf(m[rt][3], wc[3]);
        }
    }
    #pragma unroll
    for (int rt = 0; rt < RT; ++rt)
        #pragma unroll
        for (int e = 0; e < 4; ++e) {
            float mm = m[rt][e];
            #pragma unroll
            for (int d = 1; d < 16; d <<= 1)
                mm = fmaxf(mm, __shfl_xor(mm, d, 64));
            m[rt][e] = mm;
        }

    // pass 2: pruned exp-sums + mask record
    float s[RT][4];
    #pragma unroll
    for (int rt = 0; rt < RT; ++rt)
        #pragma unroll
        for (int e = 0; e < 4; ++e) s[rt][e] = 0.0f;
    sweep_sum_full<true>(A, b1p, b2p, tp, m, WINW, s, rec);

    float lsum = 0.0f;
    float lse[RT][4];
    #pragma unroll
    for (int rt = 0; rt < RT; ++rt)
        #pragma unroll
        for (int e = 0; e < 4; ++e) {
            float ss = s[rt][e];
            #pragma unroll
            for (int d = 1; d < 16; d <<= 1)
                ss += __shfl_xor(ss, d, 64);
            ss = fmaxf(ss, 1.0e-30f);
            const float l = m[rt][e] + flog2(ss);
            lsum += l;
            lse[rt][e] = l;
        }
    publish(lse, bOld, bNew, dOutX, dOutN, wbase, lane);
    return lsum;
}

// Fused half-iteration: single sweep; me = lse_prev + min(maxDrift, MEOCAP).
// LSE shift identity is exact for any me absent fp32 range issues; the cap
// bounds overshoot <= ~110 (< 126 underflow) and undershoot overflows only
// for drift > ~230 (not seen past iteration 1). MASKED walks recorded-
// active tiles only; RECORD refreshes the mask during a full sweep.
template<bool MASKED, bool RECORD>
static __device__ __forceinline__ float fused_pass(
    const __bf16* __restrict__ rH, const __bf16* __restrict__ rL,
    const __bf16* __restrict__ cH, const __bf16* __restrict__ cL,
    const float* __restrict__ tOld, const float* __restrict__ bOld,
    float* __restrict__ bNew,
    const float* __restrict__ dInX, const float* __restrict__ dInN,
    float* __restrict__ dOutX, float* __restrict__ dOutN,
    const u64* __restrict__ msk, u64* __restrict__ rec,
    const int wbase, const int lane)
{
    const int g = lane >> 4, n = lane & 15, gh = g & 1;
    bf16x8 A[RT];
    loadA(A, rH, rL, wbase, lane);

    // drift of the opposite-side messages from the preceding pass
    float dmx = dInX[lane], dmn = dInN[lane];
    #pragma unroll
    for (int d = 1; d < 64; d <<= 1) {
        dmx = fmaxf(dmx, __shfl_xor(dmx, d, 64));
        dmn = fminf(dmn, __shfl_xor(dmn, d, 64));
    }
    const float win  = WINB + fmaxf(0.0f, dmx - dmn);
    const float dmxc = fminf(dmx, MEOCAP);       // exp2-range guard

    float me[RT][4], s[RT][4];
    #pragma unroll
    for (int rt = 0; rt < RT; ++rt) {
        const f32x4 v = *(const f32x4*)(bOld + wbase + rt * 16 + g * 4);
        #pragma unroll
        for (int e = 0; e < 4; ++e) {
            me[rt][e] = (-10.0f - v[e]) + dmxc;  // lse_prev + drift bound
            s[rt][e]  = 0.0f;
        }
    }

    const __bf16* b1p = cH + n * DIM + gh * 8;
    const __bf16* b2p = cL + n * DIM + gh * 8;
    if constexpr (MASKED)
        sweep_sum_masked(A, b1p, b2p, tOld + n, me, s, msk);
    else
        sweep_sum_full<RECORD>(A, b1p, b2p, tOld + n, me, win, s, rec);

    float lsum = 0.0f;
    float lse[RT][4];
    #pragma unroll
    for (int rt = 0; rt < RT; ++rt)
        #pragma unroll
        for (int e = 0; e < 4; ++e) {
            float ss = (s[rt][e] > 1.0e-30f) ? s[rt][e] : 1.0e-30f;
            #pragma unroll
            for (int d = 1; d < 16; d <<= 1)
                ss += __shfl_xor(ss, d, 64);
            const float l = me[rt][e] + flog2(ss);
            lsum += l;
            lse[rt][e] = l;
        }
    publish(lse, bOld, bNew, dOutX, dOutN, wbase, lane);
    return lsum;
}

__global__ __launch_bounds__(THREADS)
void sinkhorn_kernel(const float* __restrict__ xg,
                     const float* __restrict__ yg,
                     float* __restrict__ out)
{
    extern __shared__ char ldsraw[];
    __bf16* sxh = (__bf16*)ldsraw;              // [1024][16] hi of K*x
    __bf16* sxl = sxh + NPTS * DIM;
    __bf16* syh = sxl + NPTS * DIM;
    __bf16* syl = syh + NPTS * DIM;
    float*  sF  = (float*)(syl + NPTS * DIM);   // [2][1024] f-messages
    float*  sG  = sF + 2 * NPTS;                // [2][1024] g-messages
    float*  sDfx = sG + 2 * NPTS;               // [2][64] f-drift max
    float*  sDfn = sDfx + 2 * 64;               // [2][64] f-drift min
    float*  sDgx = sDfn + 2 * 64;               // [2][64] g-drift max
    float*  sDgn = sDgx + 2 * 64;               // [2][64] g-drift min

    const int tid   = threadIdx.x;
    const int lane  = tid & 63;
    const int wave  = tid >> 6;
    const int wbase = wave * (RT * 16);

    const int graph = blockIdx.x / 3;
    const int term  = blockIdx.x - graph * 3;   // 0:(x,y) 1:(x,x) 2:(y,y)
    const float* xb = xg + (size_t)graph * (NPTS * DIM);
    const float* yb = yg + (size_t)graph * (NPTS * DIM);
    const float* Xp = (term == 2) ? yb : xb;
    const float* Yp = (term == 1) ? xb : yb;

    split_store(sxh, sxl, Xp, KLOG, tid);       // row side carries 1/eps scale
    split_store(syh, syl, Yp, 1.0f, tid);

    float csum;
    {
        const float hx = halfsq16(Xp + tid * DIM);
        const float hy = halfsq16(Yp + tid * DIM);
        csum = hx + hy;
        sG[NPTS + tid] = fmaf(-KLOG, hy, -10.0f);   // g_{-1} msgs -> gbuf[1]
        sF[NPTS + tid] = 0.0f;                      // finite placeholder
    }
    __syncthreads();

    u64 fmsk[RT], gmsk[RT];                      // wave-uniform tile masks
    float fsum = 0.0f, gsum = 0.0f;
    #pragma unroll 1
    for (int it = 0; it < NITERS; ++it) {
        const int cur = it & 1, alt = cur ^ 1;
        if (it < NWARM) {
            fsum = warm_pass(sxh, sxl, syh, syl, sG + alt * NPTS,
                             sF + alt * NPTS, sF + cur * NPTS,
                             sDfx + cur * 64, sDfn + cur * 64, fmsk, wbase, lane);
            gsum = warm_pass(syh, syl, sxh, sxl, sF + cur * NPTS,
                             sG + alt * NPTS, sG + cur * NPTS,
                             sDgx + cur * 64, sDgn + cur * 64, gmsk, wbase, lane);
        } else if (it == REFIT) {                // single mask refresh
            fsum = fused_pass<false, true>(sxh, sxl, syh, syl, sG + alt * NPTS,
                              sF + alt * NPTS, sF + cur * NPTS,
                              sDgx + alt * 64, sDgn + alt * 64,
                              sDfx + cur * 64, sDfn + cur * 64,
                              nullptr, fmsk, wbase, lane);
            gsum = fused_pass<false, true>(syh, syl, sxh, sxl, sF + cur * NPTS,
                              sG + alt * NPTS, sG + cur * NPTS,
                              sDfx + cur * 64, sDfn + cur * 64,
                              sDgx + cur * 64, sDgn + cur * 64,
                              nullptr, gmsk, wbase, lane);
        } else {                                  // masked fast passes
            fsum = fused_pass<true, false>(sxh, sxl, syh, syl, sG + alt * NPTS,
                              sF + alt * NPTS, sF + cur * NPTS,
                              sDgx + alt * 64, sDgn + alt * 64,
                              sDfx + cur * 64, sDfn + cur * 64,
                              fmsk, nullptr, wbase, lane);
            gsum = fused_pass<true, false>(syh, syl, sxh, sxl, sF + cur * NPTS,
                              sG + alt * NPTS, sG + cur * NPTS,
                              sDfx + cur * 64, sDfn + cur * 64,
                              sDgx + cur * 64, sDgn + cur * 64,
                              gmsk, nullptr, wbase, lane);
        }
    }
    // final f-pass i=20 (cur=0, alt=1), masked (mask from it=11, budgeted)
    fsum = fused_pass<true, false>(sxh, sxl, syh, syl, sG + 1 * NPTS,
                      sF + 1 * NPTS, sF + 0 * NPTS,
                      sDgx + 1 * 64, sDgn + 1 * 64,
                      sDfx + 0 * 64, sDfn + 0 * 64,
                      fmsk, nullptr, wbase, lane);

    // OT = [csum - CLSE*(sum lse_f + sum lse_g)] / NPTS  (lse sums x16 dup)
    float v = fmaf(-CLSE, (fsum + gsum) * (1.0f / 16.0f), csum);
    #pragma unroll
    for (int off = 32; off; off >>= 1) v += __shfl_down(v, off, 64);
    if (lane == 0) sF[NPTS + wave] = v;          // fbuf[1] is dead
    __syncthreads();
    if (tid == 0) {
        float tot = 0.0f;
        #pragma unroll
        for (int w = 0; w < NWAVES; ++w) tot += sF[NPTS + w];
        const float wgt = ((term == 0) ? 1.0f : -0.5f)
                          / ((float)GRAPHS * (float)NPTS);
        atomicAdd(out, wgt * tot);
    }
}

extern "C" void kernel_launch(void* const* d_in, const int* in_sizes, int n_in,
                              void* d_out, int out_size, void* d_ws, size_t ws_size,
                              hipStream_t stream)
{
    (void)in_sizes; (void)n_in; (void)d_ws; (void)ws_size; (void)out_size;
    const float* x = (const float*)d_in[0];
    const float* y = (const float*)d_in[1];
    float* out = (float*)d_out;

    constexpr size_t LDSB = 4 * NPTS * DIM * sizeof(__bf16)          // 128 KiB
                          + 4 * NPTS * sizeof(float)                 //  16 KiB
                          + 8 * 64 * sizeof(float);                  //   2 KiB
    hipFuncSetAttribute((const void*)sinkhorn_kernel,
                        hipFuncAttributeMaxDynamicSharedMemorySize, (int)LDSB);

    hipMemsetAsync(out, 0, sizeof(float), stream);
    hipLaunchKernelGGL(sinkhorn_kernel, dim3(GRAPHS * 3), dim3(THREADS), LDSB,
                       stream, x, y, out);
}